// Round 7
// baseline (247.749 us; speedup 1.0000x reference)
//
#include <hip/hip_runtime.h>
#include <math.h>

#define HW 65536
#define NROW 262144
#define KK 256
// EMA applied 3x in closed form: m3 = m0*r^3 + mean*(1-r)(1+r+r^2)
#define R3_F 0.997002999f
#define E3_F 0.002997001f
#define NPART 1024

typedef __attribute__((ext_vector_type(8))) short short8;
typedef __attribute__((ext_vector_type(4))) float floatx4;
typedef __attribute__((ext_vector_type(2))) unsigned int uint2v;
typedef __attribute__((ext_vector_type(4))) unsigned int uint4v;

#define MFMA16(A, B, C) __builtin_amdgcn_mfma_f32_16x16x32_bf16(A, B, C, 0, 0, 0)

union U8 { unsigned u[4]; short8 v; };

__device__ __forceinline__ unsigned short f2bf(float f) {
    unsigned u = __float_as_uint(f);
    u = (u + 0x7FFFu + ((u >> 16) & 1u)) >> 16;   // RNE
    return (unsigned short)u;
}
__device__ __forceinline__ float bf2f(unsigned hi) {   // low 16 bits used
    return __uint_as_float(hi << 16);
}
template <typename T>
__device__ __forceinline__ void nts(T v, T* p) { __builtin_nontemporal_store(v, p); }
template <typename T>
__device__ __forceinline__ T ntl(const T* p) { return __builtin_nontemporal_load(p); }

// ---------------------------------------------------------------------------
// init: m = units (fp32); mn = bf16(l2norm(units)). grid 256 x 64.
// ---------------------------------------------------------------------------
__global__ __launch_bounds__(64) void k_init(const float* __restrict__ units,
                                             float* __restrict__ m,
                                             unsigned short* __restrict__ mn) {
    int k = blockIdx.x, c = threadIdx.x;
    float v = units[(k << 6) | c];
    m[(k << 6) | c] = v;
    float ss = v * v;
#pragma unroll
    for (int off = 32; off; off >>= 1) ss += __shfl_xor(ss, off, 64);
    mn[(k << 6) | c] = f2bf(v / fmaxf(sqrtf(ss), 1e-12f));
}

// ---------------------------------------------------------------------------
// pass1 v5: stage x->LDS bf16 (256 rows/block); parallel norms (2 thr/row);
// score+argmax via MFMA with mn read DIRECTLY FROM GLOBAL (L2-hot 32 KB,
// coalesced 16B/lane) -> no mn LDS staging; coalesced nt xn write; xT
// transpose for b128 segsum gather. psums [pb][k*64+ch] nt-stored.
// LDS: 37888(xrc) + 33792(xT) + 2.3K = ~74 KB -> 2 blocks/CU. grid 1024x512.
// ---------------------------------------------------------------------------
__global__ __launch_bounds__(512, 4) void k_pass1(const float* __restrict__ x,
                                                  const unsigned short* __restrict__ mn,
                                                  unsigned short* __restrict__ psums,
                                                  float* __restrict__ pcnts,
                                                  float* __restrict__ inv_norms,
                                                  unsigned short* __restrict__ xn,
                                                  int write_xn) {
    __shared__ unsigned short xrc[256 * 74];   // [row][ch] bf16, pad 74 halves
    __shared__ unsigned short xT[64 * 264];    // transposed tile for segsum
    __shared__ unsigned int lidx[64];          // idx bytes, 256 rows
    __shared__ float lcnt[256];
    __shared__ float sInv[256];
    unsigned int* xrc32 = (unsigned int*)xrc;

    const int tid = threadIdx.x, wave = tid >> 6, lane = tid & 63;
    const int quad = lane >> 4, l15 = lane & 15;
    const int rowbase = blockIdx.x * 256;
    const int b = rowbase >> 16, p0 = rowbase & 65535;
    const float* xb = x + (((size_t)(b * 64)) << 16) + p0;

    if (tid < 256) lcnt[tid] = 0.f;

    // ---- stage x -> bf16 LDS (channel-pair packed; stride-37 u32 is 2-way) --
    {
        int cp = tid >> 4, rq = tid & 15;
        const float* xc0 = xb + (((size_t)(cp * 2)) << 16);
        const float* xc1 = xb + (((size_t)(cp * 2 + 1)) << 16);
#pragma unroll
        for (int i = 0; i < 4; i++) {
            int rg = rq + i * 16;
            float4 v0 = *(const float4*)(xc0 + rg * 4);
            float4 v1 = *(const float4*)(xc1 + rg * 4);
            xrc32[(rg * 4 + 0) * 37 + cp] = (unsigned)f2bf(v0.x) | ((unsigned)f2bf(v1.x) << 16);
            xrc32[(rg * 4 + 1) * 37 + cp] = (unsigned)f2bf(v0.y) | ((unsigned)f2bf(v1.y) << 16);
            xrc32[(rg * 4 + 2) * 37 + cp] = (unsigned)f2bf(v0.z) | ((unsigned)f2bf(v1.z) << 16);
            xrc32[(rg * 4 + 3) * 37 + cp] = (unsigned)f2bf(v0.w) | ((unsigned)f2bf(v1.w) << 16);
        }
    }
    __syncthreads();

    // ---- norms: 2 threads per row, pair-reduce via shfl_xor(1) ----
    {
        int row = tid >> 1, half = tid & 1;
        float ss = 0.f;
#pragma unroll
        for (int i = 0; i < 16; i++) {
            unsigned u = xrc32[row * 37 + half * 16 + i];
            float f0 = bf2f(u & 0xffffu), f1 = bf2f(u >> 16);
            ss += f0 * f0 + f1 * f1;
        }
        ss += __shfl_xor(ss, 1, 64);
        if (half == 0) {
            float invv = 1.0f / fmaxf(sqrtf(ss), 1e-12f);
            sInv[row] = invv;
            nts(invv, &inv_norms[rowbase + row]);
        }
    }
    __syncthreads();

    // ---- score + argmax (mn from global; raw x: scale-invariant) ----
#pragma unroll
    for (int mt = 0; mt < 2; mt++) {
        int rloc = wave * 32 + mt * 16 + l15;
        U8 a0, a1;
#pragma unroll
        for (int i = 0; i < 4; i++) {
            a0.u[i] = xrc32[rloc * 37 + quad * 4 + i];
            a1.u[i] = xrc32[rloc * 37 + 16 + quad * 4 + i];
        }
        int best[4] = {0, 0, 0, 0};
        for (int nt = 0; nt < 16; nt++) {
            const unsigned short* bp = mn + (nt * 16 + l15) * 64 + quad * 8;
            short8 b0 = *(const short8*)bp;
            short8 b1 = *(const short8*)(bp + 32);
            floatx4 acc = {0.f, 0.f, 0.f, 0.f};
            acc = MFMA16(a0.v, b0, acc);
            acc = MFMA16(a1.v, b1, acc);
#pragma unroll
            for (int rg = 0; rg < 4; rg++) {
                int pk = (__float_as_int(acc[rg] + 16.0f) & ~255) | (nt * 16 + l15);
                best[rg] = max(best[rg], pk);
            }
        }
#pragma unroll
        for (int off = 1; off <= 8; off <<= 1)
#pragma unroll
            for (int rg = 0; rg < 4; rg++)
                best[rg] = max(best[rg], __shfl_xor(best[rg], off, 64));
        if (l15 == 0) {
            unsigned v = (unsigned)(best[0] & 255) | ((unsigned)(best[1] & 255) << 8)
                       | ((unsigned)(best[2] & 255) << 16) | ((unsigned)(best[3] & 255) << 24);
            lidx[wave * 8 + mt * 4 + quad] = v;
        }
    }

    // ---- xn write: fully coalesced uint2v nt stores ----
    if (write_xn) {
        unsigned int* xnu = (unsigned int*)xn + (size_t)rowbase * 32;
#pragma unroll
        for (int i = 0; i < 8; i++) {
            int idx2 = i * 512 + tid;            // uint2 index
            int row = idx2 >> 4, c2 = idx2 & 15;
            unsigned u0 = xrc32[row * 37 + c2 * 2];
            unsigned u1 = xrc32[row * 37 + c2 * 2 + 1];
            float fv = sInv[row];
            uint2v w;
            w.x = (unsigned)f2bf(bf2f(u0 & 0xffffu) * fv) | ((unsigned)f2bf(bf2f(u0 >> 16) * fv) << 16);
            w.y = (unsigned)f2bf(bf2f(u1 & 0xffffu) * fv) | ((unsigned)f2bf(bf2f(u1 >> 16) * fv) << 16);
            nts(w, (uint2v*)(xnu + (size_t)idx2 * 2));
        }
    }

    // ---- transpose xrc -> xT[64][264] ----
    {
        int ch = tid >> 3, rb = tid & 7;
        const int cb = ch * 264, rbb = rb * 32;
#pragma unroll
        for (int w = 0; w < 4; w++) {
            int wq = ((w + rb) & 3) * 8;
            short8 t;
#pragma unroll
            for (int j = 0; j < 8; j++)
                t[j] = (short)xrc[(rbb + wq + j) * 74 + ch];
            *(short8*)&xT[cb + rbb + wq] = t;
        }
    }
    __syncthreads();

    // ---- segment-sum via one-hot MFMA (B gathered as b128 from xT) ----
    {
        int mtg = wave >> 1;     // 4 cluster-tile groups (4 tiles each)
        int ntg = wave & 1;      // 2 channel-tile groups (2 tiles each)
        floatx4 acc[4][2] = {{{0.f,0.f,0.f,0.f},{0.f,0.f,0.f,0.f}},
                             {{0.f,0.f,0.f,0.f},{0.f,0.f,0.f,0.f}},
                             {{0.f,0.f,0.f,0.f},{0.f,0.f,0.f,0.f}},
                             {{0.f,0.f,0.f,0.f},{0.f,0.f,0.f,0.f}}};
        for (int ks = 0; ks < 8; ks++) {
            unsigned id01 = lidx[ks * 8 + quad * 2 + 0];
            unsigned id23 = lidx[ks * 8 + quad * 2 + 1];
            short8 bf[2];
#pragma unroll
            for (int n = 0; n < 2; n++) {
                int ch = (ntg * 2 + n) * 16 + l15;
                bf[n] = *(const short8*)&xT[ch * 264 + ks * 32 + quad * 8];
            }
#pragma unroll
            for (int mtl = 0; mtl < 4; mtl++) {
                unsigned cl = (unsigned)((mtg * 4 + mtl) * 16 + l15);
                U8 a;
#pragma unroll
                for (int d = 0; d < 4; d++) {
                    unsigned src = (d < 2) ? id01 : id23;
                    unsigned blo = (src >> ((d & 1) * 16)) & 255u;
                    unsigned bhi = (src >> ((d & 1) * 16 + 8)) & 255u;
                    a.u[d] = (blo == cl ? 0x3F80u : 0u) | (bhi == cl ? 0x3F800000u : 0u);
                }
#pragma unroll
                for (int n = 0; n < 2; n++)
                    acc[mtl][n] = MFMA16(a.v, bf[n], acc[mtl][n]);
            }
        }
        // psums layout: [pb][k*64+ch] -> contiguous 32 KB per block, nt-stored
        unsigned short* ps = psums + (size_t)blockIdx.x * 16384;
#pragma unroll
        for (int mtl = 0; mtl < 4; mtl++) {
            int cl0 = (mtg * 4 + mtl) * 16 + quad * 4;
#pragma unroll
            for (int n = 0; n < 2; n++) {
                int ch = (ntg * 2 + n) * 16 + l15;
#pragma unroll
                for (int rg = 0; rg < 4; rg++)
                    nts(f2bf(acc[mtl][n][rg]), &ps[(cl0 + rg) * 64 + ch]);
            }
        }
    }
    // ---- counts (256 LDS atomics); pcnts layout [pb][k], nt-stored ----
    if (tid < 256) {
        unsigned myb = (lidx[tid >> 2] >> ((tid & 3) * 8)) & 255u;
        atomicAdd(&lcnt[myb], 1.0f);
    }
    __syncthreads();
    if (tid < 256) nts(lcnt[tid], &pcnts[blockIdx.x * 256 + tid]);
}

// ---------------------------------------------------------------------------
// triple-EMA update. psums [pb][16384]: block k reads each pb's 128 B k-slice
// as full-line uint4v nt loads (8/thread, 1024 threads). Emits mT bf16 [ch][k]
// so k_final_fast can stage m^T coalesced. grid 256.
// ---------------------------------------------------------------------------
__global__ __launch_bounds__(1024) void k_update3(float* __restrict__ m,
                                                  unsigned short* __restrict__ mn,
                                                  const unsigned short* __restrict__ psums,
                                                  const float* __restrict__ pcnts,
                                                  unsigned short* __restrict__ mTg) {
    __shared__ float acc8[128 * 68];   // g-stride 68 floats (bank-spread)
    __shared__ float scnt[1024];
    const int k = blockIdx.x, tid = threadIdx.x;
    const uint4v* ps4 = (const uint4v*)psums;   // pb row = 2048 uint4
    const int col = tid & 7, g = tid >> 3;      // col: uint4 within k-slice

    float s[8] = {0.f,0.f,0.f,0.f,0.f,0.f,0.f,0.f};
#pragma unroll
    for (int i = 0; i < 8; i++) {
        int pb = g + i * 128;
        uint4v v = ntl(&ps4[(size_t)pb * 2048 + k * 8 + col]);
        s[0] += bf2f(v.x & 0xffffu); s[1] += bf2f(v.x >> 16);
        s[2] += bf2f(v.y & 0xffffu); s[3] += bf2f(v.y >> 16);
        s[4] += bf2f(v.z & 0xffffu); s[5] += bf2f(v.z >> 16);
        s[6] += bf2f(v.w & 0xffffu); s[7] += bf2f(v.w >> 16);
    }
#pragma unroll
    for (int j = 0; j < 8; j++) acc8[g * 68 + col * 8 + j] = s[j];
    scnt[tid] = pcnts[tid * 256 + k];
    __syncthreads();

    if (tid < 64) {
        float tot = 0.f;
        for (int g2 = 0; g2 < 128; g2++) tot += acc8[g2 * 68 + tid];
        float cnt = 0.f;
#pragma unroll
        for (int q = 0; q < 16; q++) cnt += scnt[tid + 64 * q];
#pragma unroll
        for (int off = 32; off; off >>= 1) cnt += __shfl_xor(cnt, off, 64);
        float mean = tot / (cnt + 1e-6f);
        float v = m[(k << 6) | tid] * R3_F + mean * E3_F;
        m[(k << 6) | tid] = v;
        mTg[tid * 256 + k] = f2bf(v);
        float ss = v * v;
#pragma unroll
        for (int off = 32; off; off >>= 1) ss += __shfl_xor(ss, off, 64);
        mn[(k << 6) | tid] = f2bf(v / fmaxf(sqrtf(ss), 1e-12f));
    }
}

// ---------------------------------------------------------------------------
// final (fast) v5: swapped-operand score (S^T) makes P lane-local; P
// redistributed to the PV A-fragment with 4 shfl_xor. mn read from GLOBAL
// (L2-hot 32 KB, coalesced) -> LDS = smT only (32 KB) -> up to 4 blocks/CU
// (32 waves). xn nt-loaded, out nt-stored. grid 2048 x 512.
// ---------------------------------------------------------------------------
__global__ __launch_bounds__(512, 4) void k_final_fast(const unsigned short* __restrict__ xn,
                                                       const unsigned short* __restrict__ mn,
                                                       const unsigned short* __restrict__ mTg,
                                                       float* __restrict__ out) {
    __shared__ unsigned short smT[64 * KK];   // [ch][cluster], chunk^=(ch&7)

    const int tid = threadIdx.x;
    for (int j = tid; j < 2048; j += 512) {
        int ch = j >> 5, cp = j & 31;
        *(short8*)&smT[ch * 256 + ((cp ^ (ch & 7)) << 3)] = *(const short8*)(mTg + j * 8);
    }
    __syncthreads();

    const int wave = tid >> 6, lane = tid & 63;
    const int quad = lane >> 4, l15 = lane & 15;
    const int s7 = l15 & 7;
    const bool hi2 = (quad & 2) != 0, odd = (quad & 1) != 0;

    const int r0 = (blockIdx.x * 8 + wave) * 16;
    const int r = r0 + l15;
    const int b = r0 >> 16, p0 = r0 & 65535;

    short8 a0 = ntl((const short8*)(xn + (size_t)r * 64 + quad * 8));
    short8 a1 = ntl((const short8*)(xn + (size_t)r * 64 + 32 + quad * 8));

    float ls = 0.f;
    floatx4 oacc[4] = {{0.f,0.f,0.f,0.f},{0.f,0.f,0.f,0.f},{0.f,0.f,0.f,0.f},{0.f,0.f,0.f,0.f}};

    for (int kt2 = 0; kt2 < 8; kt2++) {
        unsigned W[2][2];
#pragma unroll
        for (int h = 0; h < 2; h++) {
            int kt = kt2 * 2 + h;
            const unsigned short* bp = mn + (kt * 16 + l15) * 64 + quad * 8;
            short8 b0 = *(const short8*)bp;
            short8 b1 = *(const short8*)(bp + 32);
            floatx4 acc = {0.f, 0.f, 0.f, 0.f};
            acc = MFMA16(b0, a0, acc);      // S^T: lane -> row l15, cluster quad*4+rg
            acc = MFMA16(b1, a1, acc);
            float e0 = __expf(acc[0]), e1 = __expf(acc[1]);
            float e2 = __expf(acc[2]), e3 = __expf(acc[3]);
            ls += (e0 + e1) + (e2 + e3);
            W[h][0] = (unsigned)f2bf(e0) | ((unsigned)f2bf(e1) << 16);
            W[h][1] = (unsigned)f2bf(e2) | ((unsigned)f2bf(e3) << 16);
        }
        // redistribute P (held: h*16+quad*4+rg) -> A-frag (needs quad*8+j)
        unsigned memA[2], memB[2];
#pragma unroll
        for (int p = 0; p < 2; p++) {
            unsigned send = hi2 ? W[0][p] : W[1][p];
            unsigned recv = (unsigned)__shfl_xor((int)send, 32, 64);
            unsigned keep = hi2 ? W[1][p] : W[0][p];
            memA[p] = hi2 ? recv : keep;
            memB[p] = hi2 ? keep : recv;
        }
        U8 ap;
#pragma unroll
        for (int p = 0; p < 2; p++) {
            unsigned send2 = odd ? memA[p] : memB[p];
            unsigned recv2 = (unsigned)__shfl_xor((int)send2, 16, 64);
            ap.u[p]     = odd ? recv2 : memA[p];
            ap.u[2 + p] = odd ? memB[p] : recv2;
        }
#pragma unroll
        for (int nt = 0; nt < 4; nt++) {
            short8 bm = *(const short8*)&smT[(nt * 16 + l15) * 256 + (((kt2 * 4 + quad) ^ s7) << 3)];
            oacc[nt] = MFMA16(ap.v, bm, oacc[nt]);
        }
    }

    ls += __shfl_xor(ls, 16, 64);
    ls += __shfl_xor(ls, 32, 64);
    float il = 1.0f / ls;
    float il4[4];
#pragma unroll
    for (int rg = 0; rg < 4; rg++) il4[rg] = __shfl(il, quad * 4 + rg, 64);

#pragma unroll
    for (int nt = 0; nt < 4; nt++) {
        floatx4 w;
#pragma unroll
        for (int rg = 0; rg < 4; rg++) w[rg] = oacc[nt][rg] * il4[rg];
        float* op = out + (((size_t)(b * 64 + nt * 16 + l15)) << 16) + p0 + quad * 4;
        nts(w, (floatx4*)op);
    }
}

// ---------------------------------------------------------------------------
// final (legacy, small-ws): re-reads x (channel-strided) + inv_norms.
// ---------------------------------------------------------------------------
__global__ __launch_bounds__(512, 4) void k_final_legacy(const float* __restrict__ x,
                                                         const unsigned short* __restrict__ mn,
                                                         const float* __restrict__ m,
                                                         const float* __restrict__ inv_norms,
                                                         float* __restrict__ out) {
    __shared__ unsigned short smn[KK * 72];
    __shared__ unsigned short smT[64 * 264];
    __shared__ unsigned short sP[8 * 640];

    const int tid = threadIdx.x;
    for (int i = tid; i < KK * 64; i += 512) smn[(i >> 6) * 72 + (i & 63)] = mn[i];
    for (int i = tid; i < KK * 64; i += 512) smT[(i & 63) * 264 + (i >> 6)] = f2bf(m[i]);
    __syncthreads();

    const int wave = tid >> 6, lane = tid & 63;
    const int quad = lane >> 4, l15 = lane & 15;

    const int r0 = (blockIdx.x * 8 + wave) * 16;
    const int r = r0 + l15;
    const int b = r0 >> 16, p0 = r0 & 65535;
    const float* xp = x + (((size_t)(b * 64)) << 16) + (p0 + l15);

    float xv[16];
#pragma unroll
    for (int j = 0; j < 8; j++) {
        xv[j]     = xp[((size_t)(quad * 8 + j)) << 16];
        xv[8 + j] = xp[((size_t)(32 + quad * 8 + j)) << 16];
    }
    const float inv = inv_norms[r];
    short8 a0, a1;
#pragma unroll
    for (int j = 0; j < 8; j++) {
        a0[j] = (short)f2bf(xv[j] * inv);
        a1[j] = (short)f2bf(xv[8 + j] * inv);
    }

    unsigned short* Pw = sP + wave * 640;
    float ls[4] = {0.f, 0.f, 0.f, 0.f};
    floatx4 oacc[4] = {{0.f,0.f,0.f,0.f},{0.f,0.f,0.f,0.f},{0.f,0.f,0.f,0.f},{0.f,0.f,0.f,0.f}};

    for (int kt2 = 0; kt2 < 8; kt2++) {
#pragma unroll
        for (int h = 0; h < 2; h++) {
            int kt = kt2 * 2 + h;
            const unsigned short* bp = &smn[(kt * 16 + l15) * 72 + quad * 8];
            short8 b0 = *(const short8*)bp;
            short8 b1 = *(const short8*)(bp + 32);
            floatx4 acc = {0.f, 0.f, 0.f, 0.f};
            acc = MFMA16(a0, b0, acc);
            acc = MFMA16(a1, b1, acc);
#pragma unroll
            for (int rg = 0; rg < 4; rg++) {
                float e = __expf(acc[rg]);
                ls[rg] += e;
                Pw[(quad * 4 + rg) * 40 + h * 16 + l15] = f2bf(e);
            }
        }
        __threadfence_block();
        short8 ap = *(const short8*)&Pw[l15 * 40 + quad * 8];
#pragma unroll
        for (int nt = 0; nt < 4; nt++) {
            short8 bm = *(const short8*)&smT[(nt * 16 + l15) * 264 + kt2 * 32 + quad * 8];
            oacc[nt] = MFMA16(ap, bm, oacc[nt]);
        }
    }

#pragma unroll
    for (int off = 1; off <= 8; off <<= 1)
#pragma unroll
        for (int rg = 0; rg < 4; rg++) ls[rg] += __shfl_xor(ls[rg], off, 64);

    float il[4];
#pragma unroll
    for (int rg = 0; rg < 4; rg++) il[rg] = 1.0f / ls[rg];

#pragma unroll
    for (int nt = 0; nt < 4; nt++) {
        floatx4 w;
#pragma unroll
        for (int rg = 0; rg < 4; rg++) w[rg] = oacc[nt][rg] * il[rg];
        float* op = out + (((size_t)(b * 64 + nt * 16 + l15)) << 16) + p0 + quad * 4;
        *(floatx4*)op = w;
    }
}

// ---------------------------------------------------------------------------
extern "C" void kernel_launch(void* const* d_in, const int* in_sizes, int n_in,
                              void* d_out, int out_size, void* d_ws, size_t ws_size,
                              hipStream_t stream) {
    (void)in_sizes; (void)n_in; (void)out_size;
    const float* x     = (const float*)d_in[0];
    const float* units = (const float*)d_in[1];
    float* out = (float*)d_out;

    // ws: m f32[16384] | inv f32[262144] | pcnts f32[1024*256] |
    //     psums bf16[1024*16384] | mn bf16[16384] | mT bf16[16384] | xn bf16[NROW*64]
    float* W = (float*)d_ws;
    float* m     = W;
    float* inv   = W + 16384;
    float* pcnts = W + 16384 + NROW;
    unsigned short* psums = (unsigned short*)(pcnts + NPART * 256);
    unsigned short* mn = psums + (size_t)NPART * 16384;
    unsigned short* mT = mn + 16384;
    unsigned short* xn = mT + 16384;

    size_t need_fast = (size_t)(16384 + NROW + NPART * 256) * 4
                     + ((size_t)NPART * 16384 + 32768) * 2
                     + (size_t)NROW * 64 * 2;
    int fast = (ws_size >= need_fast) ? 1 : 0;

    k_init<<<KK, 64, 0, stream>>>(units, m, mn);
    k_pass1<<<NPART, 512, 0, stream>>>(x, mn, psums, pcnts, inv, xn, fast);
    k_update3<<<KK, 1024, 0, stream>>>(m, mn, psums, pcnts, mT);
    if (fast) k_final_fast<<<2048, 512, 0, stream>>>(xn, mn, mT, out);
    else      k_final_legacy<<<2048, 512, 0, stream>>>(x, mn, m, inv, out);
}

// Round 8
// 182.586 us; speedup vs baseline: 1.3569x; 1.3569x over previous
//
#include <hip/hip_runtime.h>
#include <math.h>

#define HW 65536
#define NROW 262144
#define KK 256
// EMA applied 3x in closed form: m3 = m0*r^3 + mean*(1-r)(1+r+r^2)
#define R3_F 0.997002999f
#define E3_F 0.002997001f
#define NPART 1024

typedef __attribute__((ext_vector_type(8))) short short8;
typedef __attribute__((ext_vector_type(4))) float floatx4;

#define MFMA16(A, B, C) __builtin_amdgcn_mfma_f32_16x16x32_bf16(A, B, C, 0, 0, 0)

union U8 { unsigned u[4]; short8 v; };

__device__ __forceinline__ unsigned short f2bf(float f) {
    unsigned u = __float_as_uint(f);
    u = (u + 0x7FFFu + ((u >> 16) & 1u)) >> 16;   // RNE
    return (unsigned short)u;
}
__device__ __forceinline__ float bf2f(unsigned hi) {   // low 16 bits used
    return __uint_as_float(hi << 16);
}

// ---------------------------------------------------------------------------
// init: m = units (fp32); mn = bf16(l2norm(units)); zero gcnt. grid 256 x 64.
// ---------------------------------------------------------------------------
__global__ __launch_bounds__(64) void k_init(const float* __restrict__ units,
                                             float* __restrict__ m,
                                             unsigned short* __restrict__ mn,
                                             float* __restrict__ gcnt) {
    int k = blockIdx.x, c = threadIdx.x;
    int t = (k << 6) | c;
    if (t < 8192) gcnt[t] = 0.f;
    float v = units[t];
    m[t] = v;
    float ss = v * v;
#pragma unroll
    for (int off = 32; off; off >>= 1) ss += __shfl_xor(ss, off, 64);
    mn[t] = f2bf(v / fmaxf(sqrtf(ss), 1e-12f));
}

// ---------------------------------------------------------------------------
// pass1 (R6-proven + atomic counts): stage x->LDS bf16 (256 rows/block);
// norms; score+argmax via MFMA with mn in LDS; coalesced xn write; smn
// reused as xT for the one-hot segsum B-gather (ds_read_b128). psums
// [pb][k*64+ch] contiguous 32 KB/block. Counts: exact fp32 atomics into
// gcnt[k*32] (integer-valued -> order-independent). grid 1024 x 512.
// ---------------------------------------------------------------------------
__global__ __launch_bounds__(512, 4) void k_pass1(const float* __restrict__ x,
                                                  const unsigned short* __restrict__ mn,
                                                  unsigned short* __restrict__ psums,
                                                  float* __restrict__ gcnt,
                                                  float* __restrict__ inv_norms,
                                                  unsigned short* __restrict__ xn,
                                                  int write_xn) {
    __shared__ unsigned short xrc[256 * 74];   // [row][ch] bf16, pad 74 halves
    __shared__ unsigned short smn[KK * 72];    // mn (score phase); xT after
    __shared__ unsigned int lidx[64];          // idx bytes, 256 rows
    __shared__ float lcnt[256];
    __shared__ float sInv[256];
    unsigned int* xrc32 = (unsigned int*)xrc;

    const int tid = threadIdx.x, wave = tid >> 6, lane = tid & 63;
    const int quad = lane >> 4, l15 = lane & 15;
    const int rowbase = blockIdx.x * 256;
    const int b = rowbase >> 16, p0 = rowbase & 65535;
    const float* xb = x + (((size_t)(b * 64)) << 16) + p0;

    if (tid < 256) lcnt[tid] = 0.f;
    for (int i = tid; i < KK * 64; i += 512) smn[(i >> 6) * 72 + (i & 63)] = mn[i];

    // ---- stage x -> bf16 LDS (channel-pair packed; stride-37 u32 is 2-way) --
    {
        int cp = tid >> 4, rq = tid & 15;
        const float* xc0 = xb + (((size_t)(cp * 2)) << 16);
        const float* xc1 = xb + (((size_t)(cp * 2 + 1)) << 16);
#pragma unroll
        for (int i = 0; i < 4; i++) {
            int rg = rq + i * 16;
            float4 v0 = *(const float4*)(xc0 + rg * 4);
            float4 v1 = *(const float4*)(xc1 + rg * 4);
            xrc32[(rg * 4 + 0) * 37 + cp] = (unsigned)f2bf(v0.x) | ((unsigned)f2bf(v1.x) << 16);
            xrc32[(rg * 4 + 1) * 37 + cp] = (unsigned)f2bf(v0.y) | ((unsigned)f2bf(v1.y) << 16);
            xrc32[(rg * 4 + 2) * 37 + cp] = (unsigned)f2bf(v0.z) | ((unsigned)f2bf(v1.z) << 16);
            xrc32[(rg * 4 + 3) * 37 + cp] = (unsigned)f2bf(v0.w) | ((unsigned)f2bf(v1.w) << 16);
        }
    }
    __syncthreads();

    // ---- norms ----
    if (tid < 256) {
        float ss = 0.f;
#pragma unroll
        for (int i = 0; i < 32; i++) {
            unsigned u = xrc32[tid * 37 + i];
            float f0 = bf2f(u & 0xffffu), f1 = bf2f(u >> 16);
            ss += f0 * f0 + f1 * f1;
        }
        float invv = 1.0f / fmaxf(sqrtf(ss), 1e-12f);
        sInv[tid] = invv;
        inv_norms[rowbase + tid] = invv;
    }
    __syncthreads();

    // ---- score + argmax (raw x: scale-invariant; bias 16 > max|s|) ----
#pragma unroll
    for (int mt = 0; mt < 2; mt++) {
        int rloc = wave * 32 + mt * 16 + l15;
        U8 a0, a1;
#pragma unroll
        for (int i = 0; i < 4; i++) {
            a0.u[i] = xrc32[rloc * 37 + quad * 4 + i];
            a1.u[i] = xrc32[rloc * 37 + 16 + quad * 4 + i];
        }
        int best[4] = {0, 0, 0, 0};
        for (int nt = 0; nt < 16; nt++) {
            const unsigned short* bp = &smn[(nt * 16 + l15) * 72 + quad * 8];
            short8 b0 = *(const short8*)bp;
            short8 b1 = *(const short8*)(bp + 32);
            floatx4 acc = {0.f, 0.f, 0.f, 0.f};
            acc = MFMA16(a0.v, b0, acc);
            acc = MFMA16(a1.v, b1, acc);
#pragma unroll
            for (int rg = 0; rg < 4; rg++) {
                int pk = (__float_as_int(acc[rg] + 16.0f) & ~255) | (nt * 16 + l15);
                best[rg] = max(best[rg], pk);
            }
        }
#pragma unroll
        for (int off = 1; off <= 8; off <<= 1)
#pragma unroll
            for (int rg = 0; rg < 4; rg++)
                best[rg] = max(best[rg], __shfl_xor(best[rg], off, 64));
        if (l15 == 0) {
            unsigned v = (unsigned)(best[0] & 255) | ((unsigned)(best[1] & 255) << 8)
                       | ((unsigned)(best[2] & 255) << 16) | ((unsigned)(best[3] & 255) << 24);
            lidx[wave * 8 + mt * 4 + quad] = v;
        }
    }

    // ---- xn write: fully coalesced uint2 (512B/instr/wave) ----
    if (write_xn) {
        unsigned int* xnu = (unsigned int*)xn + (size_t)rowbase * 32;
#pragma unroll
        for (int i = 0; i < 8; i++) {
            int idx2 = i * 512 + tid;            // uint2 index
            int row = idx2 >> 4, c2 = idx2 & 15;
            unsigned u0 = xrc32[row * 37 + c2 * 2];
            unsigned u1 = xrc32[row * 37 + c2 * 2 + 1];
            float fv = sInv[row];
            uint2 w;
            w.x = (unsigned)f2bf(bf2f(u0 & 0xffffu) * fv) | ((unsigned)f2bf(bf2f(u0 >> 16) * fv) << 16);
            w.y = (unsigned)f2bf(bf2f(u1 & 0xffffu) * fv) | ((unsigned)f2bf(bf2f(u1 >> 16) * fv) << 16);
            *(uint2*)(xnu + (size_t)idx2 * 2) = w;
        }
    }
    __syncthreads();   // all score reads of smn done; safe to overwrite

    // ---- transpose xrc -> xT[64][264] reusing smn's buffer ----
    {
        int ch = tid >> 3, rb = tid & 7;
        unsigned short* xT = smn;
        const int cb = ch * 264, rbb = rb * 32;
#pragma unroll
        for (int w = 0; w < 4; w++) {
            int wq = ((w + rb) & 3) * 8;
            short8 t;
#pragma unroll
            for (int j = 0; j < 8; j++)
                t[j] = (short)xrc[(rbb + wq + j) * 74 + ch];
            *(short8*)&xT[cb + rbb + wq] = t;
        }
    }
    __syncthreads();

    // ---- segment-sum via one-hot MFMA (B gathered as b128 from xT) ----
    {
        const unsigned short* xT = smn;
        int mtg = wave >> 1;     // 4 cluster-tile groups (4 tiles each)
        int ntg = wave & 1;      // 2 channel-tile groups (2 tiles each)
        floatx4 acc[4][2] = {{{0.f,0.f,0.f,0.f},{0.f,0.f,0.f,0.f}},
                             {{0.f,0.f,0.f,0.f},{0.f,0.f,0.f,0.f}},
                             {{0.f,0.f,0.f,0.f},{0.f,0.f,0.f,0.f}},
                             {{0.f,0.f,0.f,0.f},{0.f,0.f,0.f,0.f}}};
        for (int ks = 0; ks < 8; ks++) {
            unsigned id01 = lidx[ks * 8 + quad * 2 + 0];
            unsigned id23 = lidx[ks * 8 + quad * 2 + 1];
            short8 bf[2];
#pragma unroll
            for (int n = 0; n < 2; n++) {
                int ch = (ntg * 2 + n) * 16 + l15;
                bf[n] = *(const short8*)&xT[ch * 264 + ks * 32 + quad * 8];
            }
#pragma unroll
            for (int mtl = 0; mtl < 4; mtl++) {
                unsigned cl = (unsigned)((mtg * 4 + mtl) * 16 + l15);
                U8 a;
#pragma unroll
                for (int d = 0; d < 4; d++) {
                    unsigned src = (d < 2) ? id01 : id23;
                    unsigned blo = (src >> ((d & 1) * 16)) & 255u;
                    unsigned bhi = (src >> ((d & 1) * 16 + 8)) & 255u;
                    a.u[d] = (blo == cl ? 0x3F80u : 0u) | (bhi == cl ? 0x3F800000u : 0u);
                }
#pragma unroll
                for (int n = 0; n < 2; n++)
                    acc[mtl][n] = MFMA16(a.v, bf[n], acc[mtl][n]);
            }
        }
        // psums layout: [pb][k*64+ch] -> contiguous 32 KB per block
        unsigned short* ps = psums + (size_t)blockIdx.x * 16384;
#pragma unroll
        for (int mtl = 0; mtl < 4; mtl++) {
            int cl0 = (mtg * 4 + mtl) * 16 + quad * 4;
#pragma unroll
            for (int n = 0; n < 2; n++) {
                int ch = (ntg * 2 + n) * 16 + l15;
#pragma unroll
                for (int rg = 0; rg < 4; rg++)
                    ps[(cl0 + rg) * 64 + ch] = f2bf(acc[mtl][n][rg]);
            }
        }
    }
    // ---- counts: 256 LDS atomics, then 256 exact global atomics ----
    if (tid < 256) {
        unsigned myb = (lidx[tid >> 2] >> ((tid & 3) * 8)) & 255u;
        atomicAdd(&lcnt[myb], 1.0f);
    }
    __syncthreads();
    if (tid < 256) atomicAdd(&gcnt[tid * 32], lcnt[tid]);   // stride-32 pad: 256 lines
}

// ---------------------------------------------------------------------------
// triple-EMA update. psums [pb][16384]: block k reads each pb's 128 B k-slice
// as full-line uint4 (8 loads/thread, 1024 threads). Count is one scalar from
// gcnt. Emits mT bf16 [ch][k] for k_final_fast staging. grid 256.
// ---------------------------------------------------------------------------
__global__ __launch_bounds__(1024) void k_update3(float* __restrict__ m,
                                                  unsigned short* __restrict__ mn,
                                                  const unsigned short* __restrict__ psums,
                                                  const float* __restrict__ gcnt,
                                                  unsigned short* __restrict__ mTg) {
    __shared__ float acc8[128 * 68];   // g-stride 68 floats (bank-spread)
    const int k = blockIdx.x, tid = threadIdx.x;
    const uint4* ps4 = (const uint4*)psums;   // pb row = 2048 uint4
    const int col = tid & 7, g = tid >> 3;    // col: uint4 within k-slice

    float s[8] = {0.f,0.f,0.f,0.f,0.f,0.f,0.f,0.f};
#pragma unroll
    for (int i = 0; i < 8; i++) {
        int pb = g + i * 128;
        uint4 v = ps4[(size_t)pb * 2048 + k * 8 + col];
        s[0] += bf2f(v.x & 0xffffu); s[1] += bf2f(v.x >> 16);
        s[2] += bf2f(v.y & 0xffffu); s[3] += bf2f(v.y >> 16);
        s[4] += bf2f(v.z & 0xffffu); s[5] += bf2f(v.z >> 16);
        s[6] += bf2f(v.w & 0xffffu); s[7] += bf2f(v.w >> 16);
    }
#pragma unroll
    for (int j = 0; j < 8; j++) acc8[g * 68 + col * 8 + j] = s[j];
    __syncthreads();

    if (tid < 64) {
        float tot = 0.f;
        for (int g2 = 0; g2 < 128; g2++) tot += acc8[g2 * 68 + tid];
        float cnt = gcnt[k * 32];
        float mean = tot / (cnt + 1e-6f);
        float v = m[(k << 6) | tid] * R3_F + mean * E3_F;
        m[(k << 6) | tid] = v;
        mTg[tid * 256 + k] = f2bf(v);
        float ss = v * v;
#pragma unroll
        for (int off = 32; off; off >>= 1) ss += __shfl_xor(ss, off, 64);
        mn[(k << 6) | tid] = f2bf(v / fmaxf(sqrtf(ss), 1e-12f));
    }
}

// ---------------------------------------------------------------------------
// final (fast) v6: R6's verified per-wave pipeline (swapped-operand S^T,
// shuffle-P, swizzled tables) at 1024 threads/block (16 waves): LDS 64 KB
// per 16 waves -> 2 blocks/CU = 32 waves/CU when VGPR<=64
// (launch_bounds(1024,4) caps at 64; kernel uses ~60). grid 1024.
// ---------------------------------------------------------------------------
__global__ __launch_bounds__(1024, 4) void k_final_fast(const unsigned short* __restrict__ xn,
                                                        const unsigned short* __restrict__ mn,
                                                        const unsigned short* __restrict__ mTg,
                                                        float* __restrict__ out) {
    __shared__ unsigned short smn[KK * 64];   // [cluster][ch], chunk^=(cluster&7)
    __shared__ unsigned short smT[64 * KK];   // [ch][cluster], chunk^=(ch&7)

    const int tid = threadIdx.x;
    for (int i = tid; i < 2048; i += 1024) {
        int row = i >> 3, c = i & 7;
        *(short8*)&smn[row * 64 + ((c ^ (row & 7)) << 3)] = *(const short8*)(mn + i * 8);
    }
    for (int j = tid; j < 2048; j += 1024) {
        int ch = j >> 5, cp = j & 31;
        *(short8*)&smT[ch * 256 + ((cp ^ (ch & 7)) << 3)] = *(const short8*)(mTg + j * 8);
    }
    __syncthreads();

    const int wave = tid >> 6, lane = tid & 63;
    const int quad = lane >> 4, l15 = lane & 15;
    const int s7 = l15 & 7;
    const bool hi2 = (quad & 2) != 0, odd = (quad & 1) != 0;

    const int r0 = (blockIdx.x * 16 + wave) * 16;
    const int r = r0 + l15;
    const int b = r0 >> 16, p0 = r0 & 65535;

    short8 a0 = *(const short8*)(xn + (size_t)r * 64 + quad * 8);
    short8 a1 = *(const short8*)(xn + (size_t)r * 64 + 32 + quad * 8);

    float ls = 0.f;
    floatx4 oacc[4] = {{0.f,0.f,0.f,0.f},{0.f,0.f,0.f,0.f},{0.f,0.f,0.f,0.f},{0.f,0.f,0.f,0.f}};

    for (int kt2 = 0; kt2 < 8; kt2++) {
        unsigned W[2][2];
#pragma unroll
        for (int h = 0; h < 2; h++) {
            int kt = kt2 * 2 + h;
            const unsigned short* bp = &smn[(kt * 16 + l15) * 64];
            short8 b0 = *(const short8*)(bp + ((quad ^ s7) << 3));
            short8 b1 = *(const short8*)(bp + (((4 + quad) ^ s7) << 3));
            floatx4 acc = {0.f, 0.f, 0.f, 0.f};
            acc = MFMA16(b0, a0, acc);      // S^T: lane -> row l15, cluster quad*4+rg
            acc = MFMA16(b1, a1, acc);
            float e0 = __expf(acc[0]), e1 = __expf(acc[1]);
            float e2 = __expf(acc[2]), e3 = __expf(acc[3]);
            ls += (e0 + e1) + (e2 + e3);
            W[h][0] = (unsigned)f2bf(e0) | ((unsigned)f2bf(e1) << 16);
            W[h][1] = (unsigned)f2bf(e2) | ((unsigned)f2bf(e3) << 16);
        }
        // redistribute P (held: h*16+quad*4+rg) -> A-frag (needs quad*8+j)
        unsigned memA[2], memB[2];
#pragma unroll
        for (int p = 0; p < 2; p++) {
            unsigned send = hi2 ? W[0][p] : W[1][p];
            unsigned recv = (unsigned)__shfl_xor((int)send, 32, 64);
            unsigned keep = hi2 ? W[1][p] : W[0][p];
            memA[p] = hi2 ? recv : keep;
            memB[p] = hi2 ? keep : recv;
        }
        U8 ap;
#pragma unroll
        for (int p = 0; p < 2; p++) {
            unsigned send2 = odd ? memA[p] : memB[p];
            unsigned recv2 = (unsigned)__shfl_xor((int)send2, 16, 64);
            ap.u[p]     = odd ? recv2 : memA[p];
            ap.u[2 + p] = odd ? memB[p] : recv2;
        }
#pragma unroll
        for (int nt = 0; nt < 4; nt++) {
            short8 bm = *(const short8*)&smT[(nt * 16 + l15) * 256 + (((kt2 * 4 + quad) ^ s7) << 3)];
            oacc[nt] = MFMA16(ap.v, bm, oacc[nt]);
        }
    }

    ls += __shfl_xor(ls, 16, 64);
    ls += __shfl_xor(ls, 32, 64);
    float il = 1.0f / ls;
    float il4[4];
#pragma unroll
    for (int rg = 0; rg < 4; rg++) il4[rg] = __shfl(il, quad * 4 + rg, 64);

#pragma unroll
    for (int nt = 0; nt < 4; nt++) {
        floatx4 w;
#pragma unroll
        for (int rg = 0; rg < 4; rg++) w[rg] = oacc[nt][rg] * il4[rg];
        float* op = out + (((size_t)(b * 64 + nt * 16 + l15)) << 16) + p0 + quad * 4;
        *(floatx4*)op = w;
    }
}

// ---------------------------------------------------------------------------
// final (legacy, small-ws): re-reads x (channel-strided) + inv_norms.
// ---------------------------------------------------------------------------
__global__ __launch_bounds__(512, 4) void k_final_legacy(const float* __restrict__ x,
                                                         const unsigned short* __restrict__ mn,
                                                         const float* __restrict__ m,
                                                         const float* __restrict__ inv_norms,
                                                         float* __restrict__ out) {
    __shared__ unsigned short smn[KK * 72];
    __shared__ unsigned short smT[64 * 264];
    __shared__ unsigned short sP[8 * 640];

    const int tid = threadIdx.x;
    for (int i = tid; i < KK * 64; i += 512) smn[(i >> 6) * 72 + (i & 63)] = mn[i];
    for (int i = tid; i < KK * 64; i += 512) smT[(i & 63) * 264 + (i >> 6)] = f2bf(m[i]);
    __syncthreads();

    const int wave = tid >> 6, lane = tid & 63;
    const int quad = lane >> 4, l15 = lane & 15;

    const int r0 = (blockIdx.x * 8 + wave) * 16;
    const int r = r0 + l15;
    const int b = r0 >> 16, p0 = r0 & 65535;
    const float* xp = x + (((size_t)(b * 64)) << 16) + (p0 + l15);

    float xv[16];
#pragma unroll
    for (int j = 0; j < 8; j++) {
        xv[j]     = xp[((size_t)(quad * 8 + j)) << 16];
        xv[8 + j] = xp[((size_t)(32 + quad * 8 + j)) << 16];
    }
    const float inv = inv_norms[r];
    short8 a0, a1;
#pragma unroll
    for (int j = 0; j < 8; j++) {
        a0[j] = (short)f2bf(xv[j] * inv);
        a1[j] = (short)f2bf(xv[8 + j] * inv);
    }

    unsigned short* Pw = sP + wave * 640;
    float ls[4] = {0.f, 0.f, 0.f, 0.f};
    floatx4 oacc[4] = {{0.f,0.f,0.f,0.f},{0.f,0.f,0.f,0.f},{0.f,0.f,0.f,0.f},{0.f,0.f,0.f,0.f}};

    for (int kt2 = 0; kt2 < 8; kt2++) {
#pragma unroll
        for (int h = 0; h < 2; h++) {
            int kt = kt2 * 2 + h;
            const unsigned short* bp = &smn[(kt * 16 + l15) * 72 + quad * 8];
            short8 b0 = *(const short8*)bp;
            short8 b1 = *(const short8*)(bp + 32);
            floatx4 acc = {0.f, 0.f, 0.f, 0.f};
            acc = MFMA16(a0, b0, acc);
            acc = MFMA16(a1, b1, acc);
#pragma unroll
            for (int rg = 0; rg < 4; rg++) {
                float e = __expf(acc[rg]);
                ls[rg] += e;
                Pw[(quad * 4 + rg) * 40 + h * 16 + l15] = f2bf(e);
            }
        }
        __threadfence_block();
        short8 ap = *(const short8*)&Pw[l15 * 40 + quad * 8];
#pragma unroll
        for (int nt = 0; nt < 4; nt++) {
            short8 bm = *(const short8*)&smT[(nt * 16 + l15) * 264 + kt2 * 32 + quad * 8];
            oacc[nt] = MFMA16(ap, bm, oacc[nt]);
        }
    }

#pragma unroll
    for (int off = 1; off <= 8; off <<= 1)
#pragma unroll
        for (int rg = 0; rg < 4; rg++) ls[rg] += __shfl_xor(ls[rg], off, 64);

    float il[4];
#pragma unroll
    for (int rg = 0; rg < 4; rg++) il[rg] = 1.0f / ls[rg];

#pragma unroll
    for (int nt = 0; nt < 4; nt++) {
        floatx4 w;
#pragma unroll
        for (int rg = 0; rg < 4; rg++) w[rg] = oacc[nt][rg] * il[rg];
        float* op = out + (((size_t)(b * 64 + nt * 16 + l15)) << 16) + p0 + quad * 4;
        *(floatx4*)op = w;
    }
}

// ---------------------------------------------------------------------------
extern "C" void kernel_launch(void* const* d_in, const int* in_sizes, int n_in,
                              void* d_out, int out_size, void* d_ws, size_t ws_size,
                              hipStream_t stream) {
    (void)in_sizes; (void)n_in; (void)out_size;
    const float* x     = (const float*)d_in[0];
    const float* units = (const float*)d_in[1];
    float* out = (float*)d_out;

    // ws: m f32[16384] | inv f32[262144] | gcnt f32[8192] |
    //     psums bf16[1024*16384] | mn bf16[16384] | mT bf16[16384] | xn bf16[NROW*64]
    float* W = (float*)d_ws;
    float* m     = W;
    float* inv   = W + 16384;
    float* gcnt  = W + 16384 + NROW;
    unsigned short* psums = (unsigned short*)(gcnt + 8192);
    unsigned short* mn = psums + (size_t)NPART * 16384;
    unsigned short* mT = mn + 16384;
    unsigned short* xn = mT + 16384;

    size_t need_fast = (size_t)(16384 + NROW + 8192) * 4
                     + ((size_t)NPART * 16384 + 32768) * 2
                     + (size_t)NROW * 64 * 2;
    int fast = (ws_size >= need_fast) ? 1 : 0;

    k_init<<<KK, 64, 0, stream>>>(units, m, mn, gcnt);
    k_pass1<<<NPART, 512, 0, stream>>>(x, mn, psums, gcnt, inv, xn, fast);
    k_update3<<<KK, 1024, 0, stream>>>(m, mn, psums, gcnt, mT);
    if (fast) k_final_fast<<<1024, 1024, 0, stream>>>(xn, mn, mT, out);
    else      k_final_legacy<<<2048, 512, 0, stream>>>(x, mn, m, inv, out);
}

// Round 9
// 180.940 us; speedup vs baseline: 1.3692x; 1.0091x over previous
//
#include <hip/hip_runtime.h>
#include <math.h>

#define HW 65536
#define NROW 262144
#define KK 256
// EMA applied 3x in closed form: m3 = m0*r^3 + mean*(1-r)(1+r+r^2)
#define R3_F 0.997002999f
#define E3_F 0.002997001f
#define NPART 1024

typedef __attribute__((ext_vector_type(8))) short short8;
typedef __attribute__((ext_vector_type(4))) float floatx4;

#define MFMA16(A, B, C) __builtin_amdgcn_mfma_f32_16x16x32_bf16(A, B, C, 0, 0, 0)

union U8 { unsigned u[4]; short8 v; };

__device__ __forceinline__ unsigned short f2bf(float f) {
    unsigned u = __float_as_uint(f);
    u = (u + 0x7FFFu + ((u >> 16) & 1u)) >> 16;   // RNE
    return (unsigned short)u;
}
__device__ __forceinline__ float bf2f(unsigned hi) {   // low 16 bits used
    return __uint_as_float(hi << 16);
}

// ---------------------------------------------------------------------------
// init: m = units (fp32); mn = bf16(l2norm(units)); zero gcnt[65536].
// grid 256 x 64.
// ---------------------------------------------------------------------------
__global__ __launch_bounds__(64) void k_init(const float* __restrict__ units,
                                             float* __restrict__ m,
                                             unsigned short* __restrict__ mn,
                                             float* __restrict__ gcnt) {
    int k = blockIdx.x, c = threadIdx.x;
    int t = (k << 6) | c;
#pragma unroll
    for (int i = 0; i < 4; i++) gcnt[t + i * 16384] = 0.f;
    float v = units[t];
    m[t] = v;
    float ss = v * v;
#pragma unroll
    for (int off = 32; off; off >>= 1) ss += __shfl_xor(ss, off, 64);
    mn[t] = f2bf(v / fmaxf(sqrtf(ss), 1e-12f));
}

// ---------------------------------------------------------------------------
// pass1 (R6-proven core): stage x->LDS bf16 (256 rows/block); norms;
// score+argmax via MFMA with mn in LDS; coalesced xn write; smn reused as xT
// for the one-hot segsum B-gather (ds_read_b128). psums [pb][k*64+ch]
// contiguous 32 KB/block. Counts: exact fp32 atomics into gcnt[k*256+slot*32]
// (8 slots by blockIdx -> 8x less line contention). grid 1024 x 512.
// ---------------------------------------------------------------------------
__global__ __launch_bounds__(512, 4) void k_pass1(const float* __restrict__ x,
                                                  const unsigned short* __restrict__ mn,
                                                  unsigned short* __restrict__ psums,
                                                  float* __restrict__ gcnt,
                                                  float* __restrict__ inv_norms,
                                                  unsigned short* __restrict__ xn,
                                                  int write_xn) {
    __shared__ unsigned short xrc[256 * 74];   // [row][ch] bf16, pad 74 halves
    __shared__ unsigned short smn[KK * 72];    // mn (score phase); xT after
    __shared__ unsigned int lidx[64];          // idx bytes, 256 rows
    __shared__ float lcnt[256];
    __shared__ float sInv[256];
    unsigned int* xrc32 = (unsigned int*)xrc;

    const int tid = threadIdx.x, wave = tid >> 6, lane = tid & 63;
    const int quad = lane >> 4, l15 = lane & 15;
    const int rowbase = blockIdx.x * 256;
    const int b = rowbase >> 16, p0 = rowbase & 65535;
    const float* xb = x + (((size_t)(b * 64)) << 16) + p0;

    if (tid < 256) lcnt[tid] = 0.f;
    for (int i = tid; i < KK * 64; i += 512) smn[(i >> 6) * 72 + (i & 63)] = mn[i];

    // ---- stage x -> bf16 LDS (channel-pair packed; stride-37 u32 is 2-way) --
    {
        int cp = tid >> 4, rq = tid & 15;
        const float* xc0 = xb + (((size_t)(cp * 2)) << 16);
        const float* xc1 = xb + (((size_t)(cp * 2 + 1)) << 16);
#pragma unroll
        for (int i = 0; i < 4; i++) {
            int rg = rq + i * 16;
            float4 v0 = *(const float4*)(xc0 + rg * 4);
            float4 v1 = *(const float4*)(xc1 + rg * 4);
            xrc32[(rg * 4 + 0) * 37 + cp] = (unsigned)f2bf(v0.x) | ((unsigned)f2bf(v1.x) << 16);
            xrc32[(rg * 4 + 1) * 37 + cp] = (unsigned)f2bf(v0.y) | ((unsigned)f2bf(v1.y) << 16);
            xrc32[(rg * 4 + 2) * 37 + cp] = (unsigned)f2bf(v0.z) | ((unsigned)f2bf(v1.z) << 16);
            xrc32[(rg * 4 + 3) * 37 + cp] = (unsigned)f2bf(v0.w) | ((unsigned)f2bf(v1.w) << 16);
        }
    }
    __syncthreads();

    // ---- norms ----
    if (tid < 256) {
        float ss = 0.f;
#pragma unroll
        for (int i = 0; i < 32; i++) {
            unsigned u = xrc32[tid * 37 + i];
            float f0 = bf2f(u & 0xffffu), f1 = bf2f(u >> 16);
            ss += f0 * f0 + f1 * f1;
        }
        float invv = 1.0f / fmaxf(sqrtf(ss), 1e-12f);
        sInv[tid] = invv;
        inv_norms[rowbase + tid] = invv;
    }
    __syncthreads();

    // ---- score + argmax (raw x: scale-invariant; bias 16 > max|s|) ----
#pragma unroll
    for (int mt = 0; mt < 2; mt++) {
        int rloc = wave * 32 + mt * 16 + l15;
        U8 a0, a1;
#pragma unroll
        for (int i = 0; i < 4; i++) {
            a0.u[i] = xrc32[rloc * 37 + quad * 4 + i];
            a1.u[i] = xrc32[rloc * 37 + 16 + quad * 4 + i];
        }
        int best[4] = {0, 0, 0, 0};
        for (int nt = 0; nt < 16; nt++) {
            const unsigned short* bp = &smn[(nt * 16 + l15) * 72 + quad * 8];
            short8 b0 = *(const short8*)bp;
            short8 b1 = *(const short8*)(bp + 32);
            floatx4 acc = {0.f, 0.f, 0.f, 0.f};
            acc = MFMA16(a0.v, b0, acc);
            acc = MFMA16(a1.v, b1, acc);
#pragma unroll
            for (int rg = 0; rg < 4; rg++) {
                int pk = (__float_as_int(acc[rg] + 16.0f) & ~255) | (nt * 16 + l15);
                best[rg] = max(best[rg], pk);
            }
        }
#pragma unroll
        for (int off = 1; off <= 8; off <<= 1)
#pragma unroll
            for (int rg = 0; rg < 4; rg++)
                best[rg] = max(best[rg], __shfl_xor(best[rg], off, 64));
        if (l15 == 0) {
            unsigned v = (unsigned)(best[0] & 255) | ((unsigned)(best[1] & 255) << 8)
                       | ((unsigned)(best[2] & 255) << 16) | ((unsigned)(best[3] & 255) << 24);
            lidx[wave * 8 + mt * 4 + quad] = v;
        }
    }

    // ---- xn write: fully coalesced uint2 (512B/instr/wave) ----
    if (write_xn) {
        unsigned int* xnu = (unsigned int*)xn + (size_t)rowbase * 32;
#pragma unroll
        for (int i = 0; i < 8; i++) {
            int idx2 = i * 512 + tid;            // uint2 index
            int row = idx2 >> 4, c2 = idx2 & 15;
            unsigned u0 = xrc32[row * 37 + c2 * 2];
            unsigned u1 = xrc32[row * 37 + c2 * 2 + 1];
            float fv = sInv[row];
            uint2 w;
            w.x = (unsigned)f2bf(bf2f(u0 & 0xffffu) * fv) | ((unsigned)f2bf(bf2f(u0 >> 16) * fv) << 16);
            w.y = (unsigned)f2bf(bf2f(u1 & 0xffffu) * fv) | ((unsigned)f2bf(bf2f(u1 >> 16) * fv) << 16);
            *(uint2*)(xnu + (size_t)idx2 * 2) = w;
        }
    }
    __syncthreads();   // all score reads of smn done; safe to overwrite

    // ---- transpose xrc -> xT[64][264] reusing smn's buffer ----
    {
        int ch = tid >> 3, rb = tid & 7;
        unsigned short* xT = smn;
        const int cb = ch * 264, rbb = rb * 32;
#pragma unroll
        for (int w = 0; w < 4; w++) {
            int wq = ((w + rb) & 3) * 8;
            short8 t;
#pragma unroll
            for (int j = 0; j < 8; j++)
                t[j] = (short)xrc[(rbb + wq + j) * 74 + ch];
            *(short8*)&xT[cb + rbb + wq] = t;
        }
    }
    __syncthreads();

    // ---- segment-sum via one-hot MFMA (B gathered as b128 from xT) ----
    {
        const unsigned short* xT = smn;
        int mtg = wave >> 1;     // 4 cluster-tile groups (4 tiles each)
        int ntg = wave & 1;      // 2 channel-tile groups (2 tiles each)
        floatx4 acc[4][2] = {{{0.f,0.f,0.f,0.f},{0.f,0.f,0.f,0.f}},
                             {{0.f,0.f,0.f,0.f},{0.f,0.f,0.f,0.f}},
                             {{0.f,0.f,0.f,0.f},{0.f,0.f,0.f,0.f}},
                             {{0.f,0.f,0.f,0.f},{0.f,0.f,0.f,0.f}}};
        for (int ks = 0; ks < 8; ks++) {
            unsigned id01 = lidx[ks * 8 + quad * 2 + 0];
            unsigned id23 = lidx[ks * 8 + quad * 2 + 1];
            short8 bf[2];
#pragma unroll
            for (int n = 0; n < 2; n++) {
                int ch = (ntg * 2 + n) * 16 + l15;
                bf[n] = *(const short8*)&xT[ch * 264 + ks * 32 + quad * 8];
            }
#pragma unroll
            for (int mtl = 0; mtl < 4; mtl++) {
                unsigned cl = (unsigned)((mtg * 4 + mtl) * 16 + l15);
                U8 a;
#pragma unroll
                for (int d = 0; d < 4; d++) {
                    unsigned src = (d < 2) ? id01 : id23;
                    unsigned blo = (src >> ((d & 1) * 16)) & 255u;
                    unsigned bhi = (src >> ((d & 1) * 16 + 8)) & 255u;
                    a.u[d] = (blo == cl ? 0x3F80u : 0u) | (bhi == cl ? 0x3F800000u : 0u);
                }
#pragma unroll
                for (int n = 0; n < 2; n++)
                    acc[mtl][n] = MFMA16(a.v, bf[n], acc[mtl][n]);
            }
        }
        // psums layout: [pb][k*64+ch] -> contiguous 32 KB per block
        unsigned short* ps = psums + (size_t)blockIdx.x * 16384;
#pragma unroll
        for (int mtl = 0; mtl < 4; mtl++) {
            int cl0 = (mtg * 4 + mtl) * 16 + quad * 4;
#pragma unroll
            for (int n = 0; n < 2; n++) {
                int ch = (ntg * 2 + n) * 16 + l15;
#pragma unroll
                for (int rg = 0; rg < 4; rg++)
                    ps[(cl0 + rg) * 64 + ch] = f2bf(acc[mtl][n][rg]);
            }
        }
    }
    // ---- counts: 256 LDS atomics, then 256 exact global atomics (8 slots) ----
    if (tid < 256) {
        unsigned myb = (lidx[tid >> 2] >> ((tid & 3) * 8)) & 255u;
        atomicAdd(&lcnt[myb], 1.0f);
    }
    __syncthreads();
    if (tid < 256) atomicAdd(&gcnt[tid * 256 + ((blockIdx.x & 7) << 5)], lcnt[tid]);
}

// ---------------------------------------------------------------------------
// sum1 (stage 1 of update): block (pg,cg) reduces 64 pb-rows of one 256-B
// column chunk of psums (coalesced 256 B/wave-read), f32 partials ->
// pacc[pg][16384]. grid 2048 (16 pg x 128 cg) x 256 = 8 blocks/CU.
// ---------------------------------------------------------------------------
__global__ __launch_bounds__(256) void k_sum1(const unsigned short* __restrict__ psums,
                                              float* __restrict__ pacc) {
    __shared__ float red[512];
    const int pg = blockIdx.x >> 7, cg = blockIdx.x & 127;
    const int tid = threadIdx.x;
    const int c = tid & 63, r = tid >> 6;
    const unsigned* pu = (const unsigned*)psums;   // pb row = 8192 u32

    float s0 = 0.f, s1 = 0.f;
#pragma unroll
    for (int i = 0; i < 16; i++) {
        unsigned u = pu[(size_t)(pg * 64 + r + i * 4) * 8192 + cg * 64 + c];
        s0 += bf2f(u & 0xffffu);
        s1 += bf2f(u >> 16);
    }
    red[tid] = s0;
    red[tid + 256] = s1;
    __syncthreads();
    if (tid < 64) {
        float t0 = red[tid] + red[tid + 64] + red[tid + 128] + red[tid + 192];
        float t1 = red[256 + tid] + red[256 + tid + 64] + red[256 + tid + 128] + red[256 + tid + 192];
        float2 w; w.x = t0; w.y = t1;
        *(float2*)&pacc[(size_t)pg * 16384 + cg * 128 + tid * 2] = w;
    }
}

// ---------------------------------------------------------------------------
// update2 (stage 2): sum 16 pg-partials + 8 count slots; triple-EMA; emit
// m (fp32), mn (bf16 normalized), mT (bf16 [ch][k]). grid 256 x 64.
// ---------------------------------------------------------------------------
__global__ __launch_bounds__(64) void k_update2(float* __restrict__ m,
                                                unsigned short* __restrict__ mn,
                                                const float* __restrict__ pacc,
                                                const float* __restrict__ gcnt,
                                                unsigned short* __restrict__ mTg) {
    const int k = blockIdx.x, c = threadIdx.x;
    float tot = 0.f;
#pragma unroll
    for (int pg = 0; pg < 16; pg++) tot += pacc[(size_t)pg * 16384 + k * 64 + c];
    float cnt = 0.f;
#pragma unroll
    for (int s = 0; s < 8; s++) cnt += gcnt[k * 256 + s * 32];
    float mean = tot / (cnt + 1e-6f);
    float v = m[(k << 6) | c] * R3_F + mean * E3_F;
    m[(k << 6) | c] = v;
    mTg[c * 256 + k] = f2bf(v);
    float ss = v * v;
#pragma unroll
    for (int off = 32; off; off >>= 1) ss += __shfl_xor(ss, off, 64);
    mn[(k << 6) | c] = f2bf(v / fmaxf(sqrtf(ss), 1e-12f));
}

// ---------------------------------------------------------------------------
// final (fast) v4 (R6-proven): swapped-operand score (S^T) makes P lane-local;
// P redistributed to the PV A-fragment with 4 shfl_xor. Both tables staged
// via coalesced chunk-swizzled b128 copies. LDS 64 KB -> 2 blocks/CU.
// grid 2048 x 512, __launch_bounds__(512,4).
// ---------------------------------------------------------------------------
__global__ __launch_bounds__(512, 4) void k_final_fast(const unsigned short* __restrict__ xn,
                                                       const unsigned short* __restrict__ mn,
                                                       const unsigned short* __restrict__ mTg,
                                                       float* __restrict__ out) {
    __shared__ unsigned short smn[KK * 64];   // [cluster][ch], chunk^=(cluster&7)
    __shared__ unsigned short smT[64 * KK];   // [ch][cluster], chunk^=(ch&7)

    const int tid = threadIdx.x;
    for (int i = tid; i < 2048; i += 512) {
        int row = i >> 3, c = i & 7;
        *(short8*)&smn[row * 64 + ((c ^ (row & 7)) << 3)] = *(const short8*)(mn + i * 8);
    }
    for (int j = tid; j < 2048; j += 512) {
        int ch = j >> 5, cp = j & 31;
        *(short8*)&smT[ch * 256 + ((cp ^ (ch & 7)) << 3)] = *(const short8*)(mTg + j * 8);
    }
    __syncthreads();

    const int wave = tid >> 6, lane = tid & 63;
    const int quad = lane >> 4, l15 = lane & 15;
    const int s7 = l15 & 7;
    const bool hi2 = (quad & 2) != 0, odd = (quad & 1) != 0;

    const int r0 = (blockIdx.x * 8 + wave) * 16;
    const int r = r0 + l15;
    const int b = r0 >> 16, p0 = r0 & 65535;

    short8 a0 = *(const short8*)(xn + (size_t)r * 64 + quad * 8);
    short8 a1 = *(const short8*)(xn + (size_t)r * 64 + 32 + quad * 8);

    float ls = 0.f;
    floatx4 oacc[4] = {{0.f,0.f,0.f,0.f},{0.f,0.f,0.f,0.f},{0.f,0.f,0.f,0.f},{0.f,0.f,0.f,0.f}};

    for (int kt2 = 0; kt2 < 8; kt2++) {
        unsigned W[2][2];
#pragma unroll
        for (int h = 0; h < 2; h++) {
            int kt = kt2 * 2 + h;
            const unsigned short* bp = &smn[(kt * 16 + l15) * 64];
            short8 b0 = *(const short8*)(bp + ((quad ^ s7) << 3));
            short8 b1 = *(const short8*)(bp + (((4 + quad) ^ s7) << 3));
            floatx4 acc = {0.f, 0.f, 0.f, 0.f};
            acc = MFMA16(b0, a0, acc);      // S^T: lane -> row l15, cluster quad*4+rg
            acc = MFMA16(b1, a1, acc);
            float e0 = __expf(acc[0]), e1 = __expf(acc[1]);
            float e2 = __expf(acc[2]), e3 = __expf(acc[3]);
            ls += (e0 + e1) + (e2 + e3);
            W[h][0] = (unsigned)f2bf(e0) | ((unsigned)f2bf(e1) << 16);
            W[h][1] = (unsigned)f2bf(e2) | ((unsigned)f2bf(e3) << 16);
        }
        // redistribute P (held: h*16+quad*4+rg) -> A-frag (needs quad*8+j)
        unsigned memA[2], memB[2];
#pragma unroll
        for (int p = 0; p < 2; p++) {
            unsigned send = hi2 ? W[0][p] : W[1][p];
            unsigned recv = (unsigned)__shfl_xor((int)send, 32, 64);
            unsigned keep = hi2 ? W[1][p] : W[0][p];
            memA[p] = hi2 ? recv : keep;
            memB[p] = hi2 ? keep : recv;
        }
        U8 ap;
#pragma unroll
        for (int p = 0; p < 2; p++) {
            unsigned send2 = odd ? memA[p] : memB[p];
            unsigned recv2 = (unsigned)__shfl_xor((int)send2, 16, 64);
            ap.u[p]     = odd ? recv2 : memA[p];
            ap.u[2 + p] = odd ? memB[p] : recv2;
        }
#pragma unroll
        for (int nt = 0; nt < 4; nt++) {
            short8 bm = *(const short8*)&smT[(nt * 16 + l15) * 256 + (((kt2 * 4 + quad) ^ s7) << 3)];
            oacc[nt] = MFMA16(ap.v, bm, oacc[nt]);
        }
    }

    ls += __shfl_xor(ls, 16, 64);
    ls += __shfl_xor(ls, 32, 64);
    float il = 1.0f / ls;
    float il4[4];
#pragma unroll
    for (int rg = 0; rg < 4; rg++) il4[rg] = __shfl(il, quad * 4 + rg, 64);

#pragma unroll
    for (int nt = 0; nt < 4; nt++) {
        floatx4 w;
#pragma unroll
        for (int rg = 0; rg < 4; rg++) w[rg] = oacc[nt][rg] * il4[rg];
        float* op = out + (((size_t)(b * 64 + nt * 16 + l15)) << 16) + p0 + quad * 4;
        *(floatx4*)op = w;
    }
}

// ---------------------------------------------------------------------------
// final (legacy, small-ws): re-reads x (channel-strided) + inv_norms.
// ---------------------------------------------------------------------------
__global__ __launch_bounds__(512, 4) void k_final_legacy(const float* __restrict__ x,
                                                         const unsigned short* __restrict__ mn,
                                                         const float* __restrict__ m,
                                                         const float* __restrict__ inv_norms,
                                                         float* __restrict__ out) {
    __shared__ unsigned short smn[KK * 72];
    __shared__ unsigned short smT[64 * 264];
    __shared__ unsigned short sP[8 * 640];

    const int tid = threadIdx.x;
    for (int i = tid; i < KK * 64; i += 512) smn[(i >> 6) * 72 + (i & 63)] = mn[i];
    for (int i = tid; i < KK * 64; i += 512) smT[(i & 63) * 264 + (i >> 6)] = f2bf(m[i]);
    __syncthreads();

    const int wave = tid >> 6, lane = tid & 63;
    const int quad = lane >> 4, l15 = lane & 15;

    const int r0 = (blockIdx.x * 8 + wave) * 16;
    const int r = r0 + l15;
    const int b = r0 >> 16, p0 = r0 & 65535;
    const float* xp = x + (((size_t)(b * 64)) << 16) + (p0 + l15);

    float xv[16];
#pragma unroll
    for (int j = 0; j < 8; j++) {
        xv[j]     = xp[((size_t)(quad * 8 + j)) << 16];
        xv[8 + j] = xp[((size_t)(32 + quad * 8 + j)) << 16];
    }
    const float inv = inv_norms[r];
    short8 a0, a1;
#pragma unroll
    for (int j = 0; j < 8; j++) {
        a0[j] = (short)f2bf(xv[j] * inv);
        a1[j] = (short)f2bf(xv[8 + j] * inv);
    }

    unsigned short* Pw = sP + wave * 640;
    float ls[4] = {0.f, 0.f, 0.f, 0.f};
    floatx4 oacc[4] = {{0.f,0.f,0.f,0.f},{0.f,0.f,0.f,0.f},{0.f,0.f,0.f,0.f},{0.f,0.f,0.f,0.f}};

    for (int kt2 = 0; kt2 < 8; kt2++) {
#pragma unroll
        for (int h = 0; h < 2; h++) {
            int kt = kt2 * 2 + h;
            const unsigned short* bp = &smn[(kt * 16 + l15) * 72 + quad * 8];
            short8 b0 = *(const short8*)bp;
            short8 b1 = *(const short8*)(bp + 32);
            floatx4 acc = {0.f, 0.f, 0.f, 0.f};
            acc = MFMA16(a0, b0, acc);
            acc = MFMA16(a1, b1, acc);
#pragma unroll
            for (int rg = 0; rg < 4; rg++) {
                float e = __expf(acc[rg]);
                ls[rg] += e;
                Pw[(quad * 4 + rg) * 40 + h * 16 + l15] = f2bf(e);
            }
        }
        __threadfence_block();
        short8 ap = *(const short8*)&Pw[l15 * 40 + quad * 8];
#pragma unroll
        for (int nt = 0; nt < 4; nt++) {
            short8 bm = *(const short8*)&smT[(nt * 16 + l15) * 264 + kt2 * 32 + quad * 8];
            oacc[nt] = MFMA16(ap, bm, oacc[nt]);
        }
    }

#pragma unroll
    for (int off = 1; off <= 8; off <<= 1)
#pragma unroll
        for (int rg = 0; rg < 4; rg++) ls[rg] += __shfl_xor(ls[rg], off, 64);

    float il[4];
#pragma unroll
    for (int rg = 0; rg < 4; rg++) il[rg] = 1.0f / ls[rg];

#pragma unroll
    for (int nt = 0; nt < 4; nt++) {
        floatx4 w;
#pragma unroll
        for (int rg = 0; rg < 4; rg++) w[rg] = oacc[nt][rg] * il[rg];
        float* op = out + (((size_t)(b * 64 + nt * 16 + l15)) << 16) + p0 + quad * 4;
        *(floatx4*)op = w;
    }
}

// ---------------------------------------------------------------------------
extern "C" void kernel_launch(void* const* d_in, const int* in_sizes, int n_in,
                              void* d_out, int out_size, void* d_ws, size_t ws_size,
                              hipStream_t stream) {
    (void)in_sizes; (void)n_in; (void)out_size;
    const float* x     = (const float*)d_in[0];
    const float* units = (const float*)d_in[1];
    float* out = (float*)d_out;

    // ws: m f32[16384] | inv f32[NROW] | gcnt f32[65536] | pacc f32[16*16384] |
    //     psums bf16[1024*16384] | mn bf16[16384] | mT bf16[16384] | xn bf16[NROW*64]
    float* W = (float*)d_ws;
    float* m     = W;
    float* inv   = W + 16384;
    float* gcnt  = W + 16384 + NROW;
    float* pacc  = gcnt + 65536;
    unsigned short* psums = (unsigned short*)(pacc + 16 * 16384);
    unsigned short* mn = psums + (size_t)NPART * 16384;
    unsigned short* mT = mn + 16384;
    unsigned short* xn = mT + 16384;

    size_t need_fast = (size_t)(16384 + NROW + 65536 + 16 * 16384) * 4
                     + ((size_t)NPART * 16384 + 32768) * 2
                     + (size_t)NROW * 64 * 2;
    int fast = (ws_size >= need_fast) ? 1 : 0;

    k_init<<<KK, 64, 0, stream>>>(units, m, mn, gcnt);
    k_pass1<<<NPART, 512, 0, stream>>>(x, mn, psums, gcnt, inv, xn, fast);
    k_sum1<<<2048, 256, 0, stream>>>(psums, pacc);
    k_update2<<<KK, 64, 0, stream>>>(m, mn, pacc, gcnt, mT);
    if (fast) k_final_fast<<<2048, 512, 0, stream>>>(xn, mn, mT, out);
    else      k_final_legacy<<<2048, 512, 0, stream>>>(x, mn, m, inv, out);
}

// Round 10
// 177.073 us; speedup vs baseline: 1.3991x; 1.0218x over previous
//
#include <hip/hip_runtime.h>
#include <math.h>

#define HW 65536
#define NROW 262144
#define KK 256
// EMA applied 3x in closed form: m3 = m0*r^3 + mean*(1-r)(1+r+r^2)
#define R3_F 0.997002999f
#define E3_F 0.002997001f
#define NPART 1024

typedef __attribute__((ext_vector_type(8))) short short8;
typedef __attribute__((ext_vector_type(4))) float floatx4;

#define MFMA16(A, B, C) __builtin_amdgcn_mfma_f32_16x16x32_bf16(A, B, C, 0, 0, 0)

union U8 { unsigned u[4]; short8 v; };

__device__ __forceinline__ unsigned short f2bf(float f) {
    unsigned u = __float_as_uint(f);
    u = (u + 0x7FFFu + ((u >> 16) & 1u)) >> 16;   // RNE
    return (unsigned short)u;
}
__device__ __forceinline__ float bf2f(unsigned hi) {   // low 16 bits used
    return __uint_as_float(hi << 16);
}

// ---------------------------------------------------------------------------
// pass1 (R6-proven core, init folded in): mn table computed IN-BLOCK from
// units (64KB L2-hot, coalesced; replaces the global-mn staging loop);
// stage x->LDS bf16 (256 rows/block); norms; score+argmax via MFMA; coalesced
// xn write; smn reused as xT for the one-hot segsum B-gather (ds_read_b128).
// psums [pb][k*64+ch] contiguous 32 KB/block; pcnts [pb][k] contiguous.
// grid 1024 x 512.
// ---------------------------------------------------------------------------
__global__ __launch_bounds__(512, 4) void k_pass1(const float* __restrict__ x,
                                                  const float* __restrict__ units,
                                                  unsigned short* __restrict__ psums,
                                                  float* __restrict__ pcnts,
                                                  float* __restrict__ inv_norms,
                                                  unsigned short* __restrict__ xn,
                                                  int write_xn) {
    __shared__ unsigned short xrc[256 * 74];   // [row][ch] bf16, pad 74 halves
    __shared__ unsigned short smn[KK * 72];    // mn (score phase); xT after
    __shared__ unsigned int lidx[64];          // idx bytes, 256 rows
    __shared__ float lcnt[256];
    __shared__ float sInv[256];
    unsigned int* xrc32 = (unsigned int*)xrc;

    const int tid = threadIdx.x, wave = tid >> 6, lane = tid & 63;
    const int quad = lane >> 4, l15 = lane & 15;
    const int rowbase = blockIdx.x * 256;
    const int b = rowbase >> 16, p0 = rowbase & 65535;
    const float* xb = x + (((size_t)(b * 64)) << 16) + p0;

    if (tid < 256) lcnt[tid] = 0.f;

    // ---- mn table in-block: row k = tid>>1, half = tid&1 (32 ch each) ----
    {
        int row = tid >> 1, half = tid & 1;
        const float* up = units + row * 64 + half * 32;
        float4 uv[8];
        float ss = 0.f;
#pragma unroll
        for (int i = 0; i < 8; i++) {
            uv[i] = *(const float4*)(up + i * 4);
            ss += uv[i].x * uv[i].x + uv[i].y * uv[i].y
                + uv[i].z * uv[i].z + uv[i].w * uv[i].w;
        }
        ss += __shfl_xor(ss, 1, 64);
        float invn = 1.0f / fmaxf(sqrtf(ss), 1e-12f);
        unsigned* s32 = (unsigned*)smn;
        int base = row * 36 + half * 16;
#pragma unroll
        for (int i = 0; i < 8; i++) {
            s32[base + i * 2]     = (unsigned)f2bf(uv[i].x * invn) | ((unsigned)f2bf(uv[i].y * invn) << 16);
            s32[base + i * 2 + 1] = (unsigned)f2bf(uv[i].z * invn) | ((unsigned)f2bf(uv[i].w * invn) << 16);
        }
    }

    // ---- stage x -> bf16 LDS (channel-pair packed; stride-37 u32 is 2-way) --
    {
        int cp = tid >> 4, rq = tid & 15;
        const float* xc0 = xb + (((size_t)(cp * 2)) << 16);
        const float* xc1 = xb + (((size_t)(cp * 2 + 1)) << 16);
#pragma unroll
        for (int i = 0; i < 4; i++) {
            int rg = rq + i * 16;
            float4 v0 = *(const float4*)(xc0 + rg * 4);
            float4 v1 = *(const float4*)(xc1 + rg * 4);
            xrc32[(rg * 4 + 0) * 37 + cp] = (unsigned)f2bf(v0.x) | ((unsigned)f2bf(v1.x) << 16);
            xrc32[(rg * 4 + 1) * 37 + cp] = (unsigned)f2bf(v0.y) | ((unsigned)f2bf(v1.y) << 16);
            xrc32[(rg * 4 + 2) * 37 + cp] = (unsigned)f2bf(v0.z) | ((unsigned)f2bf(v1.z) << 16);
            xrc32[(rg * 4 + 3) * 37 + cp] = (unsigned)f2bf(v0.w) | ((unsigned)f2bf(v1.w) << 16);
        }
    }
    __syncthreads();

    // ---- norms ----
    if (tid < 256) {
        float ss = 0.f;
#pragma unroll
        for (int i = 0; i < 32; i++) {
            unsigned u = xrc32[tid * 37 + i];
            float f0 = bf2f(u & 0xffffu), f1 = bf2f(u >> 16);
            ss += f0 * f0 + f1 * f1;
        }
        float invv = 1.0f / fmaxf(sqrtf(ss), 1e-12f);
        sInv[tid] = invv;
        if (!write_xn) inv_norms[rowbase + tid] = invv;
    }
    __syncthreads();

    // ---- score + argmax (raw x: scale-invariant; bias 16 > max|s|) ----
#pragma unroll
    for (int mt = 0; mt < 2; mt++) {
        int rloc = wave * 32 + mt * 16 + l15;
        U8 a0, a1;
#pragma unroll
        for (int i = 0; i < 4; i++) {
            a0.u[i] = xrc32[rloc * 37 + quad * 4 + i];
            a1.u[i] = xrc32[rloc * 37 + 16 + quad * 4 + i];
        }
        int best[4] = {0, 0, 0, 0};
        for (int nt = 0; nt < 16; nt++) {
            const unsigned short* bp = &smn[(nt * 16 + l15) * 72 + quad * 8];
            short8 b0 = *(const short8*)bp;
            short8 b1 = *(const short8*)(bp + 32);
            floatx4 acc = {0.f, 0.f, 0.f, 0.f};
            acc = MFMA16(a0.v, b0, acc);
            acc = MFMA16(a1.v, b1, acc);
#pragma unroll
            for (int rg = 0; rg < 4; rg++) {
                int pk = (__float_as_int(acc[rg] + 16.0f) & ~255) | (nt * 16 + l15);
                best[rg] = max(best[rg], pk);
            }
        }
#pragma unroll
        for (int off = 1; off <= 8; off <<= 1)
#pragma unroll
            for (int rg = 0; rg < 4; rg++)
                best[rg] = max(best[rg], __shfl_xor(best[rg], off, 64));
        if (l15 == 0) {
            unsigned v = (unsigned)(best[0] & 255) | ((unsigned)(best[1] & 255) << 8)
                       | ((unsigned)(best[2] & 255) << 16) | ((unsigned)(best[3] & 255) << 24);
            lidx[wave * 8 + mt * 4 + quad] = v;
        }
    }

    // ---- xn write: fully coalesced uint2 (512B/instr/wave) ----
    if (write_xn) {
        unsigned int* xnu = (unsigned int*)xn + (size_t)rowbase * 32;
#pragma unroll
        for (int i = 0; i < 8; i++) {
            int idx2 = i * 512 + tid;            // uint2 index
            int row = idx2 >> 4, c2 = idx2 & 15;
            unsigned u0 = xrc32[row * 37 + c2 * 2];
            unsigned u1 = xrc32[row * 37 + c2 * 2 + 1];
            float fv = sInv[row];
            uint2 w;
            w.x = (unsigned)f2bf(bf2f(u0 & 0xffffu) * fv) | ((unsigned)f2bf(bf2f(u0 >> 16) * fv) << 16);
            w.y = (unsigned)f2bf(bf2f(u1 & 0xffffu) * fv) | ((unsigned)f2bf(bf2f(u1 >> 16) * fv) << 16);
            *(uint2*)(xnu + (size_t)idx2 * 2) = w;
        }
    }
    __syncthreads();   // all score reads of smn done; safe to overwrite

    // ---- transpose xrc -> xT[64][264] reusing smn's buffer ----
    {
        int ch = tid >> 3, rb = tid & 7;
        unsigned short* xT = smn;
        const int cb = ch * 264, rbb = rb * 32;
#pragma unroll
        for (int w = 0; w < 4; w++) {
            int wq = ((w + rb) & 3) * 8;
            short8 t;
#pragma unroll
            for (int j = 0; j < 8; j++)
                t[j] = (short)xrc[(rbb + wq + j) * 74 + ch];
            *(short8*)&xT[cb + rbb + wq] = t;
        }
    }
    __syncthreads();

    // ---- segment-sum via one-hot MFMA (B gathered as b128 from xT) ----
    {
        const unsigned short* xT = smn;
        int mtg = wave >> 1;     // 4 cluster-tile groups (4 tiles each)
        int ntg = wave & 1;      // 2 channel-tile groups (2 tiles each)
        floatx4 acc[4][2] = {{{0.f,0.f,0.f,0.f},{0.f,0.f,0.f,0.f}},
                             {{0.f,0.f,0.f,0.f},{0.f,0.f,0.f,0.f}},
                             {{0.f,0.f,0.f,0.f},{0.f,0.f,0.f,0.f}},
                             {{0.f,0.f,0.f,0.f},{0.f,0.f,0.f,0.f}}};
        for (int ks = 0; ks < 8; ks++) {
            unsigned id01 = lidx[ks * 8 + quad * 2 + 0];
            unsigned id23 = lidx[ks * 8 + quad * 2 + 1];
            short8 bf[2];
#pragma unroll
            for (int n = 0; n < 2; n++) {
                int ch = (ntg * 2 + n) * 16 + l15;
                bf[n] = *(const short8*)&xT[ch * 264 + ks * 32 + quad * 8];
            }
#pragma unroll
            for (int mtl = 0; mtl < 4; mtl++) {
                unsigned cl = (unsigned)((mtg * 4 + mtl) * 16 + l15);
                U8 a;
#pragma unroll
                for (int d = 0; d < 4; d++) {
                    unsigned src = (d < 2) ? id01 : id23;
                    unsigned blo = (src >> ((d & 1) * 16)) & 255u;
                    unsigned bhi = (src >> ((d & 1) * 16 + 8)) & 255u;
                    a.u[d] = (blo == cl ? 0x3F80u : 0u) | (bhi == cl ? 0x3F800000u : 0u);
                }
#pragma unroll
                for (int n = 0; n < 2; n++)
                    acc[mtl][n] = MFMA16(a.v, bf[n], acc[mtl][n]);
            }
        }
        // psums layout: [pb][k*64+ch] -> contiguous 32 KB per block
        unsigned short* ps = psums + (size_t)blockIdx.x * 16384;
#pragma unroll
        for (int mtl = 0; mtl < 4; mtl++) {
            int cl0 = (mtg * 4 + mtl) * 16 + quad * 4;
#pragma unroll
            for (int n = 0; n < 2; n++) {
                int ch = (ntg * 2 + n) * 16 + l15;
#pragma unroll
                for (int rg = 0; rg < 4; rg++)
                    ps[(cl0 + rg) * 64 + ch] = f2bf(acc[mtl][n][rg]);
            }
        }
    }
    // ---- counts (256 LDS atomics); pcnts layout [pb][k] ----
    if (tid < 256) {
        unsigned myb = (lidx[tid >> 2] >> ((tid & 3) * 8)) & 255u;
        atomicAdd(&lcnt[myb], 1.0f);
    }
    __syncthreads();
    if (tid < 256) pcnts[blockIdx.x * 256 + tid] = lcnt[tid];
}

// ---------------------------------------------------------------------------
// triple-EMA update (R6-proven). psums [pb][16384]: block k reads each pb's
// 128 B k-slice as full-line uint4 (8 loads/thread, 1024 threads). EMA reads
// units directly (m was an untouched copy); writes m (legacy), mn, mT.
// grid 256.
// ---------------------------------------------------------------------------
__global__ __launch_bounds__(1024) void k_update3(const float* __restrict__ units,
                                                  float* __restrict__ m,
                                                  unsigned short* __restrict__ mn,
                                                  const unsigned short* __restrict__ psums,
                                                  const float* __restrict__ pcnts,
                                                  unsigned short* __restrict__ mTg) {
    __shared__ float acc8[128 * 68];   // g-stride 68 floats (bank-spread)
    __shared__ float scnt[1024];
    const int k = blockIdx.x, tid = threadIdx.x;
    const uint4* ps4 = (const uint4*)psums;   // pb row = 2048 uint4
    const int col = tid & 7, g = tid >> 3;    // col: uint4 within k-slice

    float s[8] = {0.f,0.f,0.f,0.f,0.f,0.f,0.f,0.f};
#pragma unroll
    for (int i = 0; i < 8; i++) {
        int pb = g + i * 128;
        uint4 v = ps4[(size_t)pb * 2048 + k * 8 + col];
        s[0] += bf2f(v.x & 0xffffu); s[1] += bf2f(v.x >> 16);
        s[2] += bf2f(v.y & 0xffffu); s[3] += bf2f(v.y >> 16);
        s[4] += bf2f(v.z & 0xffffu); s[5] += bf2f(v.z >> 16);
        s[6] += bf2f(v.w & 0xffffu); s[7] += bf2f(v.w >> 16);
    }
#pragma unroll
    for (int j = 0; j < 8; j++) acc8[g * 68 + col * 8 + j] = s[j];
    scnt[tid] = pcnts[tid * 256 + k];
    __syncthreads();

    if (tid < 64) {
        float tot = 0.f;
        for (int g2 = 0; g2 < 128; g2++) tot += acc8[g2 * 68 + tid];
        float cnt = 0.f;
#pragma unroll
        for (int q = 0; q < 16; q++) cnt += scnt[tid + 64 * q];
#pragma unroll
        for (int off = 32; off; off >>= 1) cnt += __shfl_xor(cnt, off, 64);
        float mean = tot / (cnt + 1e-6f);
        float v = units[(k << 6) | tid] * R3_F + mean * E3_F;
        m[(k << 6) | tid] = v;
        mTg[tid * 256 + k] = f2bf(v);
        float ss = v * v;
#pragma unroll
        for (int off = 32; off; off >>= 1) ss += __shfl_xor(ss, off, 64);
        mn[(k << 6) | tid] = f2bf(v / fmaxf(sqrtf(ss), 1e-12f));
    }
}

// ---------------------------------------------------------------------------
// final (fast) v4 (R6-proven): swapped-operand score (S^T) makes P lane-local;
// P redistributed to the PV A-fragment with 4 shfl_xor. Both tables staged
// via coalesced chunk-swizzled b128 copies. LDS 64 KB -> 2 blocks/CU.
// grid 2048 x 512, __launch_bounds__(512,4).
// ---------------------------------------------------------------------------
__global__ __launch_bounds__(512, 4) void k_final_fast(const unsigned short* __restrict__ xn,
                                                       const unsigned short* __restrict__ mn,
                                                       const unsigned short* __restrict__ mTg,
                                                       float* __restrict__ out) {
    __shared__ unsigned short smn[KK * 64];   // [cluster][ch], chunk^=(cluster&7)
    __shared__ unsigned short smT[64 * KK];   // [ch][cluster], chunk^=(ch&7)

    const int tid = threadIdx.x;
    for (int i = tid; i < 2048; i += 512) {
        int row = i >> 3, c = i & 7;
        *(short8*)&smn[row * 64 + ((c ^ (row & 7)) << 3)] = *(const short8*)(mn + i * 8);
    }
    for (int j = tid; j < 2048; j += 512) {
        int ch = j >> 5, cp = j & 31;
        *(short8*)&smT[ch * 256 + ((cp ^ (ch & 7)) << 3)] = *(const short8*)(mTg + j * 8);
    }
    __syncthreads();

    const int wave = tid >> 6, lane = tid & 63;
    const int quad = lane >> 4, l15 = lane & 15;
    const int s7 = l15 & 7;
    const bool hi2 = (quad & 2) != 0, odd = (quad & 1) != 0;

    const int r0 = (blockIdx.x * 8 + wave) * 16;
    const int r = r0 + l15;
    const int b = r0 >> 16, p0 = r0 & 65535;

    short8 a0 = *(const short8*)(xn + (size_t)r * 64 + quad * 8);
    short8 a1 = *(const short8*)(xn + (size_t)r * 64 + 32 + quad * 8);

    float ls = 0.f;
    floatx4 oacc[4] = {{0.f,0.f,0.f,0.f},{0.f,0.f,0.f,0.f},{0.f,0.f,0.f,0.f},{0.f,0.f,0.f,0.f}};

    for (int kt2 = 0; kt2 < 8; kt2++) {
        unsigned W[2][2];
#pragma unroll
        for (int h = 0; h < 2; h++) {
            int kt = kt2 * 2 + h;
            const unsigned short* bp = &smn[(kt * 16 + l15) * 64];
            short8 b0 = *(const short8*)(bp + ((quad ^ s7) << 3));
            short8 b1 = *(const short8*)(bp + (((4 + quad) ^ s7) << 3));
            floatx4 acc = {0.f, 0.f, 0.f, 0.f};
            acc = MFMA16(b0, a0, acc);      // S^T: lane -> row l15, cluster quad*4+rg
            acc = MFMA16(b1, a1, acc);
            float e0 = __expf(acc[0]), e1 = __expf(acc[1]);
            float e2 = __expf(acc[2]), e3 = __expf(acc[3]);
            ls += (e0 + e1) + (e2 + e3);
            W[h][0] = (unsigned)f2bf(e0) | ((unsigned)f2bf(e1) << 16);
            W[h][1] = (unsigned)f2bf(e2) | ((unsigned)f2bf(e3) << 16);
        }
        // redistribute P (held: h*16+quad*4+rg) -> A-frag (needs quad*8+j)
        unsigned memA[2], memB[2];
#pragma unroll
        for (int p = 0; p < 2; p++) {
            unsigned send = hi2 ? W[0][p] : W[1][p];
            unsigned recv = (unsigned)__shfl_xor((int)send, 32, 64);
            unsigned keep = hi2 ? W[1][p] : W[0][p];
            memA[p] = hi2 ? recv : keep;
            memB[p] = hi2 ? keep : recv;
        }
        U8 ap;
#pragma unroll
        for (int p = 0; p < 2; p++) {
            unsigned send2 = odd ? memA[p] : memB[p];
            unsigned recv2 = (unsigned)__shfl_xor((int)send2, 16, 64);
            ap.u[p]     = odd ? recv2 : memA[p];
            ap.u[2 + p] = odd ? memB[p] : recv2;
        }
#pragma unroll
        for (int nt = 0; nt < 4; nt++) {
            short8 bm = *(const short8*)&smT[(nt * 16 + l15) * 256 + (((kt2 * 4 + quad) ^ s7) << 3)];
            oacc[nt] = MFMA16(ap.v, bm, oacc[nt]);
        }
    }

    ls += __shfl_xor(ls, 16, 64);
    ls += __shfl_xor(ls, 32, 64);
    float il = 1.0f / ls;
    float il4[4];
#pragma unroll
    for (int rg = 0; rg < 4; rg++) il4[rg] = __shfl(il, quad * 4 + rg, 64);

#pragma unroll
    for (int nt = 0; nt < 4; nt++) {
        floatx4 w;
#pragma unroll
        for (int rg = 0; rg < 4; rg++) w[rg] = oacc[nt][rg] * il4[rg];
        float* op = out + (((size_t)(b * 64 + nt * 16 + l15)) << 16) + p0 + quad * 4;
        *(floatx4*)op = w;
    }
}

// ---------------------------------------------------------------------------
// final (legacy, small-ws): re-reads x (channel-strided) + inv_norms.
// ---------------------------------------------------------------------------
__global__ __launch_bounds__(512, 4) void k_final_legacy(const float* __restrict__ x,
                                                         const unsigned short* __restrict__ mn,
                                                         const float* __restrict__ m,
                                                         const float* __restrict__ inv_norms,
                                                         float* __restrict__ out) {
    __shared__ unsigned short smn[KK * 72];
    __shared__ unsigned short smT[64 * 264];
    __shared__ unsigned short sP[8 * 640];

    const int tid = threadIdx.x;
    for (int i = tid; i < KK * 64; i += 512) smn[(i >> 6) * 72 + (i & 63)] = mn[i];
    for (int i = tid; i < KK * 64; i += 512) smT[(i & 63) * 264 + (i >> 6)] = f2bf(m[i]);
    __syncthreads();

    const int wave = tid >> 6, lane = tid & 63;
    const int quad = lane >> 4, l15 = lane & 15;

    const int r0 = (blockIdx.x * 8 + wave) * 16;
    const int r = r0 + l15;
    const int b = r0 >> 16, p0 = r0 & 65535;
    const float* xp = x + (((size_t)(b * 64)) << 16) + (p0 + l15);

    float xv[16];
#pragma unroll
    for (int j = 0; j < 8; j++) {
        xv[j]     = xp[((size_t)(quad * 8 + j)) << 16];
        xv[8 + j] = xp[((size_t)(32 + quad * 8 + j)) << 16];
    }
    const float inv = inv_norms[r];
    short8 a0, a1;
#pragma unroll
    for (int j = 0; j < 8; j++) {
        a0[j] = (short)f2bf(xv[j] * inv);
        a1[j] = (short)f2bf(xv[8 + j] * inv);
    }

    unsigned short* Pw = sP + wave * 640;
    float ls[4] = {0.f, 0.f, 0.f, 0.f};
    floatx4 oacc[4] = {{0.f,0.f,0.f,0.f},{0.f,0.f,0.f,0.f},{0.f,0.f,0.f,0.f},{0.f,0.f,0.f,0.f}};

    for (int kt2 = 0; kt2 < 8; kt2++) {
#pragma unroll
        for (int h = 0; h < 2; h++) {
            int kt = kt2 * 2 + h;
            const unsigned short* bp = &smn[(kt * 16 + l15) * 72 + quad * 8];
            short8 b0 = *(const short8*)bp;
            short8 b1 = *(const short8*)(bp + 32);
            floatx4 acc = {0.f, 0.f, 0.f, 0.f};
            acc = MFMA16(a0, b0, acc);
            acc = MFMA16(a1, b1, acc);
#pragma unroll
            for (int rg = 0; rg < 4; rg++) {
                float e = __expf(acc[rg]);
                ls[rg] += e;
                Pw[(quad * 4 + rg) * 40 + h * 16 + l15] = f2bf(e);
            }
        }
        __threadfence_block();
        short8 ap = *(const short8*)&Pw[l15 * 40 + quad * 8];
#pragma unroll
        for (int nt = 0; nt < 4; nt++) {
            short8 bm = *(const short8*)&smT[(nt * 16 + l15) * 264 + kt2 * 32 + quad * 8];
            oacc[nt] = MFMA16(ap, bm, oacc[nt]);
        }
    }

#pragma unroll
    for (int off = 1; off <= 8; off <<= 1)
#pragma unroll
        for (int rg = 0; rg < 4; rg++) ls[rg] += __shfl_xor(ls[rg], off, 64);

    float il[4];
#pragma unroll
    for (int rg = 0; rg < 4; rg++) il[rg] = 1.0f / ls[rg];

#pragma unroll
    for (int nt = 0; nt < 4; nt++) {
        floatx4 w;
#pragma unroll
        for (int rg = 0; rg < 4; rg++) w[rg] = oacc[nt][rg] * il[rg];
        float* op = out + (((size_t)(b * 64 + nt * 16 + l15)) << 16) + p0 + quad * 4;
        *(floatx4*)op = w;
    }
}

// ---------------------------------------------------------------------------
extern "C" void kernel_launch(void* const* d_in, const int* in_sizes, int n_in,
                              void* d_out, int out_size, void* d_ws, size_t ws_size,
                              hipStream_t stream) {
    (void)in_sizes; (void)n_in; (void)out_size;
    const float* x     = (const float*)d_in[0];
    const float* units = (const float*)d_in[1];
    float* out = (float*)d_out;

    // ws: m f32[16384] | inv f32[NROW] | pcnts f32[1024*256] |
    //     psums bf16[1024*16384] | mn bf16[16384] | mT bf16[16384] | xn bf16[NROW*64]
    float* W = (float*)d_ws;
    float* m     = W;
    float* inv   = W + 16384;
    float* pcnts = W + 16384 + NROW;
    unsigned short* psums = (unsigned short*)(pcnts + NPART * 256);
    unsigned short* mn = psums + (size_t)NPART * 16384;
    unsigned short* mT = mn + 16384;
    unsigned short* xn = mT + 16384;

    size_t need_fast = (size_t)(16384 + NROW + NPART * 256) * 4
                     + ((size_t)NPART * 16384 + 32768) * 2
                     + (size_t)NROW * 64 * 2;
    int fast = (ws_size >= need_fast) ? 1 : 0;

    k_pass1<<<NPART, 512, 0, stream>>>(x, units, psums, pcnts, inv, xn, fast);
    k_update3<<<KK, 1024, 0, stream>>>(units, m, mn, psums, pcnts, mT);
    if (fast) k_final_fast<<<2048, 512, 0, stream>>>(xn, mn, mT, out);
    else      k_final_legacy<<<2048, 512, 0, stream>>>(x, mn, m, inv, out);
}

// Round 11
// 173.279 us; speedup vs baseline: 1.4298x; 1.0219x over previous
//
#include <hip/hip_runtime.h>
#include <math.h>

#define HW 65536
#define NROW 262144
#define KK 256
// EMA applied 3x in closed form: m3 = m0*r^3 + mean*(1-r)(1+r+r^2)
#define R3_F 0.997002999f
#define E3_F 0.002997001f
#define NPART 1024

typedef __attribute__((ext_vector_type(8))) short short8;
typedef __attribute__((ext_vector_type(4))) float floatx4;

#define MFMA16(A, B, C) __builtin_amdgcn_mfma_f32_16x16x32_bf16(A, B, C, 0, 0, 0)

union U8 { unsigned u[4]; short8 v; };

__device__ __forceinline__ unsigned short f2bf(float f) {
    unsigned u = __float_as_uint(f);
    u = (u + 0x7FFFu + ((u >> 16) & 1u)) >> 16;   // RNE
    return (unsigned short)u;
}
__device__ __forceinline__ float bf2f(unsigned hi) {   // low 16 bits used
    return __uint_as_float(hi << 16);
}

// ---------------------------------------------------------------------------
// pass1 (R10 core, segsum rebalanced): mn table computed IN-BLOCK from units;
// stage x->LDS bf16; norms; score+argmax via MFMA; coalesced xn write; smn
// reused as xT. Segsum: 8 cluster-groups (1/wave) x all 4 channel-quarters
// -> one-hot built 16x/thread (was 32x), bytes hoisted per-ks.
// psums [pb][k*64+ch]; pcnts [pb][k]. grid 1024 x 512.
// ---------------------------------------------------------------------------
__global__ __launch_bounds__(512, 4) void k_pass1(const float* __restrict__ x,
                                                  const float* __restrict__ units,
                                                  unsigned short* __restrict__ psums,
                                                  float* __restrict__ pcnts,
                                                  float* __restrict__ inv_norms,
                                                  unsigned short* __restrict__ xn,
                                                  int write_xn) {
    __shared__ unsigned short xrc[256 * 74];   // [row][ch] bf16, pad 74 halves
    __shared__ unsigned short smn[KK * 72];    // mn (score phase); xT after
    __shared__ unsigned int lidx[64];          // idx bytes, 256 rows
    __shared__ float lcnt[256];
    __shared__ float sInv[256];
    unsigned int* xrc32 = (unsigned int*)xrc;

    const int tid = threadIdx.x, wave = tid >> 6, lane = tid & 63;
    const int quad = lane >> 4, l15 = lane & 15;
    const int rowbase = blockIdx.x * 256;
    const int b = rowbase >> 16, p0 = rowbase & 65535;
    const float* xb = x + (((size_t)(b * 64)) << 16) + p0;

    if (tid < 256) lcnt[tid] = 0.f;

    // ---- mn table in-block: row k = tid>>1, half = tid&1 (32 ch each) ----
    {
        int row = tid >> 1, half = tid & 1;
        const float* up = units + row * 64 + half * 32;
        float4 uv[8];
        float ss = 0.f;
#pragma unroll
        for (int i = 0; i < 8; i++) {
            uv[i] = *(const float4*)(up + i * 4);
            ss += uv[i].x * uv[i].x + uv[i].y * uv[i].y
                + uv[i].z * uv[i].z + uv[i].w * uv[i].w;
        }
        ss += __shfl_xor(ss, 1, 64);
        float invn = 1.0f / fmaxf(sqrtf(ss), 1e-12f);
        unsigned* s32 = (unsigned*)smn;
        int base = row * 36 + half * 16;
#pragma unroll
        for (int i = 0; i < 8; i++) {
            s32[base + i * 2]     = (unsigned)f2bf(uv[i].x * invn) | ((unsigned)f2bf(uv[i].y * invn) << 16);
            s32[base + i * 2 + 1] = (unsigned)f2bf(uv[i].z * invn) | ((unsigned)f2bf(uv[i].w * invn) << 16);
        }
    }

    // ---- stage x -> bf16 LDS (channel-pair packed; stride-37 u32 is 2-way) --
    {
        int cp = tid >> 4, rq = tid & 15;
        const float* xc0 = xb + (((size_t)(cp * 2)) << 16);
        const float* xc1 = xb + (((size_t)(cp * 2 + 1)) << 16);
#pragma unroll
        for (int i = 0; i < 4; i++) {
            int rg = rq + i * 16;
            float4 v0 = *(const float4*)(xc0 + rg * 4);
            float4 v1 = *(const float4*)(xc1 + rg * 4);
            xrc32[(rg * 4 + 0) * 37 + cp] = (unsigned)f2bf(v0.x) | ((unsigned)f2bf(v1.x) << 16);
            xrc32[(rg * 4 + 1) * 37 + cp] = (unsigned)f2bf(v0.y) | ((unsigned)f2bf(v1.y) << 16);
            xrc32[(rg * 4 + 2) * 37 + cp] = (unsigned)f2bf(v0.z) | ((unsigned)f2bf(v1.z) << 16);
            xrc32[(rg * 4 + 3) * 37 + cp] = (unsigned)f2bf(v0.w) | ((unsigned)f2bf(v1.w) << 16);
        }
    }
    __syncthreads();

    // ---- norms ----
    if (tid < 256) {
        float ss = 0.f;
#pragma unroll
        for (int i = 0; i < 32; i++) {
            unsigned u = xrc32[tid * 37 + i];
            float f0 = bf2f(u & 0xffffu), f1 = bf2f(u >> 16);
            ss += f0 * f0 + f1 * f1;
        }
        float invv = 1.0f / fmaxf(sqrtf(ss), 1e-12f);
        sInv[tid] = invv;
        if (!write_xn) inv_norms[rowbase + tid] = invv;
    }
    __syncthreads();

    // ---- score + argmax (raw x: scale-invariant; bias 16 > max|s|) ----
#pragma unroll
    for (int mt = 0; mt < 2; mt++) {
        int rloc = wave * 32 + mt * 16 + l15;
        U8 a0, a1;
#pragma unroll
        for (int i = 0; i < 4; i++) {
            a0.u[i] = xrc32[rloc * 37 + quad * 4 + i];
            a1.u[i] = xrc32[rloc * 37 + 16 + quad * 4 + i];
        }
        int best[4] = {0, 0, 0, 0};
        for (int nt = 0; nt < 16; nt++) {
            const unsigned short* bp = &smn[(nt * 16 + l15) * 72 + quad * 8];
            short8 b0 = *(const short8*)bp;
            short8 b1 = *(const short8*)(bp + 32);
            floatx4 acc = {0.f, 0.f, 0.f, 0.f};
            acc = MFMA16(a0.v, b0, acc);
            acc = MFMA16(a1.v, b1, acc);
#pragma unroll
            for (int rg = 0; rg < 4; rg++) {
                int pk = (__float_as_int(acc[rg] + 16.0f) & ~255) | (nt * 16 + l15);
                best[rg] = max(best[rg], pk);
            }
        }
#pragma unroll
        for (int off = 1; off <= 8; off <<= 1)
#pragma unroll
            for (int rg = 0; rg < 4; rg++)
                best[rg] = max(best[rg], __shfl_xor(best[rg], off, 64));
        if (l15 == 0) {
            unsigned v = (unsigned)(best[0] & 255) | ((unsigned)(best[1] & 255) << 8)
                       | ((unsigned)(best[2] & 255) << 16) | ((unsigned)(best[3] & 255) << 24);
            lidx[wave * 8 + mt * 4 + quad] = v;
        }
    }

    // ---- xn write: fully coalesced uint2 (512B/instr/wave) ----
    if (write_xn) {
        unsigned int* xnu = (unsigned int*)xn + (size_t)rowbase * 32;
#pragma unroll
        for (int i = 0; i < 8; i++) {
            int idx2 = i * 512 + tid;            // uint2 index
            int row = idx2 >> 4, c2 = idx2 & 15;
            unsigned u0 = xrc32[row * 37 + c2 * 2];
            unsigned u1 = xrc32[row * 37 + c2 * 2 + 1];
            float fv = sInv[row];
            uint2 w;
            w.x = (unsigned)f2bf(bf2f(u0 & 0xffffu) * fv) | ((unsigned)f2bf(bf2f(u0 >> 16) * fv) << 16);
            w.y = (unsigned)f2bf(bf2f(u1 & 0xffffu) * fv) | ((unsigned)f2bf(bf2f(u1 >> 16) * fv) << 16);
            *(uint2*)(xnu + (size_t)idx2 * 2) = w;
        }
    }
    __syncthreads();   // all score reads of smn done; safe to overwrite

    // ---- transpose xrc -> xT[64][264] reusing smn's buffer ----
    {
        int ch = tid >> 3, rb = tid & 7;
        unsigned short* xT = smn;
        const int cb = ch * 264, rbb = rb * 32;
#pragma unroll
        for (int w = 0; w < 4; w++) {
            int wq = ((w + rb) & 3) * 8;
            short8 t;
#pragma unroll
            for (int j = 0; j < 8; j++)
                t[j] = (short)xrc[(rbb + wq + j) * 74 + ch];
            *(short8*)&xT[cb + rbb + wq] = t;
        }
    }
    __syncthreads();

    // ---- segment-sum via one-hot MFMA: 8 cluster-groups (1/wave) x 4 ch-
    // quarters; one-hot built 16x/thread, bytes extracted once per ks ----
    {
        const unsigned short* xT = smn;
        floatx4 acc[2][4] = {{{0.f,0.f,0.f,0.f},{0.f,0.f,0.f,0.f},{0.f,0.f,0.f,0.f},{0.f,0.f,0.f,0.f}},
                             {{0.f,0.f,0.f,0.f},{0.f,0.f,0.f,0.f},{0.f,0.f,0.f,0.f},{0.f,0.f,0.f,0.f}}};
        for (int ks = 0; ks < 8; ks++) {
            unsigned id01 = lidx[ks * 8 + quad * 2 + 0];
            unsigned id23 = lidx[ks * 8 + quad * 2 + 1];
            unsigned by[8];
            by[0] = id01 & 255u; by[1] = (id01 >> 8) & 255u;
            by[2] = (id01 >> 16) & 255u; by[3] = id01 >> 24;
            by[4] = id23 & 255u; by[5] = (id23 >> 8) & 255u;
            by[6] = (id23 >> 16) & 255u; by[7] = id23 >> 24;
            short8 bf[4];
#pragma unroll
            for (int n = 0; n < 4; n++) {
                int ch = n * 16 + l15;
                bf[n] = *(const short8*)&xT[ch * 264 + ks * 32 + quad * 8];
            }
#pragma unroll
            for (int mtl = 0; mtl < 2; mtl++) {
                unsigned cl = (unsigned)(wave * 32 + mtl * 16 + l15);
                U8 a;
#pragma unroll
                for (int d = 0; d < 4; d++)
                    a.u[d] = (by[2 * d] == cl ? 0x3F80u : 0u)
                           | (by[2 * d + 1] == cl ? 0x3F800000u : 0u);
#pragma unroll
                for (int n = 0; n < 4; n++)
                    acc[mtl][n] = MFMA16(a.v, bf[n], acc[mtl][n]);
            }
        }
        // psums layout: [pb][k*64+ch] -> contiguous 32 KB per block
        unsigned short* ps = psums + (size_t)blockIdx.x * 16384;
#pragma unroll
        for (int mtl = 0; mtl < 2; mtl++) {
            int cl0 = wave * 32 + mtl * 16 + quad * 4;
#pragma unroll
            for (int n = 0; n < 4; n++) {
                int ch = n * 16 + l15;
#pragma unroll
                for (int rg = 0; rg < 4; rg++)
                    ps[(cl0 + rg) * 64 + ch] = f2bf(acc[mtl][n][rg]);
            }
        }
    }
    // ---- counts (256 LDS atomics); pcnts layout [pb][k] ----
    if (tid < 256) {
        unsigned myb = (lidx[tid >> 2] >> ((tid & 3) * 8)) & 255u;
        atomicAdd(&lcnt[myb], 1.0f);
    }
    __syncthreads();
    if (tid < 256) pcnts[blockIdx.x * 256 + tid] = lcnt[tid];
}

// ---------------------------------------------------------------------------
// triple-EMA update (R6-proven). psums [pb][16384]: block k reads each pb's
// 128 B k-slice as full-line uint4 (8 loads/thread, 1024 threads). EMA reads
// units directly; writes m (legacy), mn, mT. grid 256.
// ---------------------------------------------------------------------------
__global__ __launch_bounds__(1024) void k_update3(const float* __restrict__ units,
                                                  float* __restrict__ m,
                                                  unsigned short* __restrict__ mn,
                                                  const unsigned short* __restrict__ psums,
                                                  const float* __restrict__ pcnts,
                                                  unsigned short* __restrict__ mTg) {
    __shared__ float acc8[128 * 68];   // g-stride 68 floats (bank-spread)
    __shared__ float scnt[1024];
    const int k = blockIdx.x, tid = threadIdx.x;
    const uint4* ps4 = (const uint4*)psums;   // pb row = 2048 uint4
    const int col = tid & 7, g = tid >> 3;    // col: uint4 within k-slice

    float s[8] = {0.f,0.f,0.f,0.f,0.f,0.f,0.f,0.f};
#pragma unroll
    for (int i = 0; i < 8; i++) {
        int pb = g + i * 128;
        uint4 v = ps4[(size_t)pb * 2048 + k * 8 + col];
        s[0] += bf2f(v.x & 0xffffu); s[1] += bf2f(v.x >> 16);
        s[2] += bf2f(v.y & 0xffffu); s[3] += bf2f(v.y >> 16);
        s[4] += bf2f(v.z & 0xffffu); s[5] += bf2f(v.z >> 16);
        s[6] += bf2f(v.w & 0xffffu); s[7] += bf2f(v.w >> 16);
    }
#pragma unroll
    for (int j = 0; j < 8; j++) acc8[g * 68 + col * 8 + j] = s[j];
    scnt[tid] = pcnts[tid * 256 + k];
    __syncthreads();

    if (tid < 64) {
        float tot = 0.f;
        for (int g2 = 0; g2 < 128; g2++) tot += acc8[g2 * 68 + tid];
        float cnt = 0.f;
#pragma unroll
        for (int q = 0; q < 16; q++) cnt += scnt[tid + 64 * q];
#pragma unroll
        for (int off = 32; off; off >>= 1) cnt += __shfl_xor(cnt, off, 64);
        float mean = tot / (cnt + 1e-6f);
        float v = units[(k << 6) | tid] * R3_F + mean * E3_F;
        m[(k << 6) | tid] = v;
        mTg[tid * 256 + k] = f2bf(v);
        float ss = v * v;
#pragma unroll
        for (int off = 32; off; off >>= 1) ss += __shfl_xor(ss, off, 64);
        mn[(k << 6) | tid] = f2bf(v / fmaxf(sqrtf(ss), 1e-12f));
    }
}

// ---------------------------------------------------------------------------
// final (fast) v4 (R6-proven): swapped-operand score (S^T) makes P lane-local;
// P redistributed to the PV A-fragment with 4 shfl_xor. Both tables staged
// via coalesced chunk-swizzled b128 copies. LDS 64 KB -> 2 blocks/CU.
// grid 2048 x 512, __launch_bounds__(512,4).
// ---------------------------------------------------------------------------
__global__ __launch_bounds__(512, 4) void k_final_fast(const unsigned short* __restrict__ xn,
                                                       const unsigned short* __restrict__ mn,
                                                       const unsigned short* __restrict__ mTg,
                                                       float* __restrict__ out) {
    __shared__ unsigned short smn[KK * 64];   // [cluster][ch], chunk^=(cluster&7)
    __shared__ unsigned short smT[64 * KK];   // [ch][cluster], chunk^=(ch&7)

    const int tid = threadIdx.x;
    for (int i = tid; i < 2048; i += 512) {
        int row = i >> 3, c = i & 7;
        *(short8*)&smn[row * 64 + ((c ^ (row & 7)) << 3)] = *(const short8*)(mn + i * 8);
    }
    for (int j = tid; j < 2048; j += 512) {
        int ch = j >> 5, cp = j & 31;
        *(short8*)&smT[ch * 256 + ((cp ^ (ch & 7)) << 3)] = *(const short8*)(mTg + j * 8);
    }
    __syncthreads();

    const int wave = tid >> 6, lane = tid & 63;
    const int quad = lane >> 4, l15 = lane & 15;
    const int s7 = l15 & 7;
    const bool hi2 = (quad & 2) != 0, odd = (quad & 1) != 0;

    const int r0 = (blockIdx.x * 8 + wave) * 16;
    const int r = r0 + l15;
    const int b = r0 >> 16, p0 = r0 & 65535;

    short8 a0 = *(const short8*)(xn + (size_t)r * 64 + quad * 8);
    short8 a1 = *(const short8*)(xn + (size_t)r * 64 + 32 + quad * 8);

    float ls = 0.f;
    floatx4 oacc[4] = {{0.f,0.f,0.f,0.f},{0.f,0.f,0.f,0.f},{0.f,0.f,0.f,0.f},{0.f,0.f,0.f,0.f}};

    for (int kt2 = 0; kt2 < 8; kt2++) {
        unsigned W[2][2];
#pragma unroll
        for (int h = 0; h < 2; h++) {
            int kt = kt2 * 2 + h;
            const unsigned short* bp = &smn[(kt * 16 + l15) * 64];
            short8 b0 = *(const short8*)(bp + ((quad ^ s7) << 3));
            short8 b1 = *(const short8*)(bp + (((4 + quad) ^ s7) << 3));
            floatx4 acc = {0.f, 0.f, 0.f, 0.f};
            acc = MFMA16(b0, a0, acc);      // S^T: lane -> row l15, cluster quad*4+rg
            acc = MFMA16(b1, a1, acc);
            float e0 = __expf(acc[0]), e1 = __expf(acc[1]);
            float e2 = __expf(acc[2]), e3 = __expf(acc[3]);
            ls += (e0 + e1) + (e2 + e3);
            W[h][0] = (unsigned)f2bf(e0) | ((unsigned)f2bf(e1) << 16);
            W[h][1] = (unsigned)f2bf(e2) | ((unsigned)f2bf(e3) << 16);
        }
        // redistribute P (held: h*16+quad*4+rg) -> A-frag (needs quad*8+j)
        unsigned memA[2], memB[2];
#pragma unroll
        for (int p = 0; p < 2; p++) {
            unsigned send = hi2 ? W[0][p] : W[1][p];
            unsigned recv = (unsigned)__shfl_xor((int)send, 32, 64);
            unsigned keep = hi2 ? W[1][p] : W[0][p];
            memA[p] = hi2 ? recv : keep;
            memB[p] = hi2 ? keep : recv;
        }
        U8 ap;
#pragma unroll
        for (int p = 0; p < 2; p++) {
            unsigned send2 = odd ? memA[p] : memB[p];
            unsigned recv2 = (unsigned)__shfl_xor((int)send2, 16, 64);
            ap.u[p]     = odd ? recv2 : memA[p];
            ap.u[2 + p] = odd ? memB[p] : recv2;
        }
#pragma unroll
        for (int nt = 0; nt < 4; nt++) {
            short8 bm = *(const short8*)&smT[(nt * 16 + l15) * 256 + (((kt2 * 4 + quad) ^ s7) << 3)];
            oacc[nt] = MFMA16(ap.v, bm, oacc[nt]);
        }
    }

    ls += __shfl_xor(ls, 16, 64);
    ls += __shfl_xor(ls, 32, 64);
    float il = 1.0f / ls;
    float il4[4];
#pragma unroll
    for (int rg = 0; rg < 4; rg++) il4[rg] = __shfl(il, quad * 4 + rg, 64);

#pragma unroll
    for (int nt = 0; nt < 4; nt++) {
        floatx4 w;
#pragma unroll
        for (int rg = 0; rg < 4; rg++) w[rg] = oacc[nt][rg] * il4[rg];
        float* op = out + (((size_t)(b * 64 + nt * 16 + l15)) << 16) + p0 + quad * 4;
        *(floatx4*)op = w;
    }
}

// ---------------------------------------------------------------------------
// final (legacy, small-ws): re-reads x (channel-strided) + inv_norms.
// ---------------------------------------------------------------------------
__global__ __launch_bounds__(512, 4) void k_final_legacy(const float* __restrict__ x,
                                                         const unsigned short* __restrict__ mn,
                                                         const float* __restrict__ m,
                                                         const float* __restrict__ inv_norms,
                                                         float* __restrict__ out) {
    __shared__ unsigned short smn[KK * 72];
    __shared__ unsigned short smT[64 * 264];
    __shared__ unsigned short sP[8 * 640];

    const int tid = threadIdx.x;
    for (int i = tid; i < KK * 64; i += 512) smn[(i >> 6) * 72 + (i & 63)] = mn[i];
    for (int i = tid; i < KK * 64; i += 512) smT[(i & 63) * 264 + (i >> 6)] = f2bf(m[i]);
    __syncthreads();

    const int wave = tid >> 6, lane = tid & 63;
    const int quad = lane >> 4, l15 = lane & 15;

    const int r0 = (blockIdx.x * 8 + wave) * 16;
    const int r = r0 + l15;
    const int b = r0 >> 16, p0 = r0 & 65535;
    const float* xp = x + (((size_t)(b * 64)) << 16) + (p0 + l15);

    float xv[16];
#pragma unroll
    for (int j = 0; j < 8; j++) {
        xv[j]     = xp[((size_t)(quad * 8 + j)) << 16];
        xv[8 + j] = xp[((size_t)(32 + quad * 8 + j)) << 16];
    }
    const float inv = inv_norms[r];
    short8 a0, a1;
#pragma unroll
    for (int j = 0; j < 8; j++) {
        a0[j] = (short)f2bf(xv[j] * inv);
        a1[j] = (short)f2bf(xv[8 + j] * inv);
    }

    unsigned short* Pw = sP + wave * 640;
    float ls[4] = {0.f, 0.f, 0.f, 0.f};
    floatx4 oacc[4] = {{0.f,0.f,0.f,0.f},{0.f,0.f,0.f,0.f},{0.f,0.f,0.f,0.f},{0.f,0.f,0.f,0.f}};

    for (int kt2 = 0; kt2 < 8; kt2++) {
#pragma unroll
        for (int h = 0; h < 2; h++) {
            int kt = kt2 * 2 + h;
            const unsigned short* bp = &smn[(kt * 16 + l15) * 72 + quad * 8];
            short8 b0 = *(const short8*)bp;
            short8 b1 = *(const short8*)(bp + 32);
            floatx4 acc = {0.f, 0.f, 0.f, 0.f};
            acc = MFMA16(a0, b0, acc);
            acc = MFMA16(a1, b1, acc);
#pragma unroll
            for (int rg = 0; rg < 4; rg++) {
                float e = __expf(acc[rg]);
                ls[rg] += e;
                Pw[(quad * 4 + rg) * 40 + h * 16 + l15] = f2bf(e);
            }
        }
        __threadfence_block();
        short8 ap = *(const short8*)&Pw[l15 * 40 + quad * 8];
#pragma unroll
        for (int nt = 0; nt < 4; nt++) {
            short8 bm = *(const short8*)&smT[(nt * 16 + l15) * 264 + kt2 * 32 + quad * 8];
            oacc[nt] = MFMA16(ap, bm, oacc[nt]);
        }
    }

#pragma unroll
    for (int off = 1; off <= 8; off <<= 1)
#pragma unroll
        for (int rg = 0; rg < 4; rg++) ls[rg] += __shfl_xor(ls[rg], off, 64);

    float il[4];
#pragma unroll
    for (int rg = 0; rg < 4; rg++) il[rg] = 1.0f / ls[rg];

#pragma unroll
    for (int nt = 0; nt < 4; nt++) {
        floatx4 w;
#pragma unroll
        for (int rg = 0; rg < 4; rg++) w[rg] = oacc[nt][rg] * il[rg];
        float* op = out + (((size_t)(b * 64 + nt * 16 + l15)) << 16) + p0 + quad * 4;
        *(floatx4*)op = w;
    }
}

// ---------------------------------------------------------------------------
extern "C" void kernel_launch(void* const* d_in, const int* in_sizes, int n_in,
                              void* d_out, int out_size, void* d_ws, size_t ws_size,
                              hipStream_t stream) {
    (void)in_sizes; (void)n_in; (void)out_size;
    const float* x     = (const float*)d_in[0];
    const float* units = (const float*)d_in[1];
    float* out = (float*)d_out;

    // ws: m f32[16384] | inv f32[NROW] | pcnts f32[1024*256] |
    //     psums bf16[1024*16384] | mn bf16[16384] | mT bf16[16384] | xn bf16[NROW*64]
    float* W = (float*)d_ws;
    float* m     = W;
    float* inv   = W + 16384;
    float* pcnts = W + 16384 + NROW;
    unsigned short* psums = (unsigned short*)(pcnts + NPART * 256);
    unsigned short* mn = psums + (size_t)NPART * 16384;
    unsigned short* mT = mn + 16384;
    unsigned short* xn = mT + 16384;

    size_t need_fast = (size_t)(16384 + NROW + NPART * 256) * 4
                     + ((size_t)NPART * 16384 + 32768) * 2
                     + (size_t)NROW * 64 * 2;
    int fast = (ws_size >= need_fast) ? 1 : 0;

    k_pass1<<<NPART, 512, 0, stream>>>(x, units, psums, pcnts, inv, xn, fast);
    k_update3<<<KK, 1024, 0, stream>>>(units, m, mn, psums, pcnts, mT);
    if (fast) k_final_fast<<<2048, 512, 0, stream>>>(xn, mn, mT, out);
    else      k_final_legacy<<<2048, 512, 0, stream>>>(x, mn, m, inv, out);
}

// Round 12
// 172.638 us; speedup vs baseline: 1.4351x; 1.0037x over previous
//
#include <hip/hip_runtime.h>
#include <math.h>

#define HW 65536
#define NROW 262144
#define KK 256
// EMA applied 3x in closed form: m3 = m0*r^3 + mean*(1-r)(1+r+r^2)
#define R3_F 0.997002999f
#define E3_F 0.002997001f
#define NPART 1024

typedef __attribute__((ext_vector_type(8))) short short8;
typedef __attribute__((ext_vector_type(4))) float floatx4;

#define MFMA16(A, B, C) __builtin_amdgcn_mfma_f32_16x16x32_bf16(A, B, C, 0, 0, 0)

union U8 { unsigned u[4]; short8 v; };

__device__ __forceinline__ unsigned short f2bf(float f) {
    unsigned u = __float_as_uint(f);
    u = (u + 0x7FFFu + ((u >> 16) & 1u)) >> 16;   // RNE
    return (unsigned short)u;
}
__device__ __forceinline__ float bf2f(unsigned hi) {   // low 16 bits used
    return __uint_as_float(hi << 16);
}

// ---------------------------------------------------------------------------
// pass1 (R11 core + bias-seeded argmax + parallel norms): mn table computed
// IN-BLOCK from units; stage x->LDS bf16; norms (2 thr/row); score+argmax via
// MFMA with C seeded to 16.0 (bias folded into accumulator -> no per-element
// add); coalesced xn write; smn reused as xT. Segsum: 8 cluster-groups x 4
// channel-quarters, one-hot built 16x/thread, bytes hoisted per-ks.
// psums [pb][k*64+ch]; pcnts [pb][k]. grid 1024 x 512.
// ---------------------------------------------------------------------------
__global__ __launch_bounds__(512, 4) void k_pass1(const float* __restrict__ x,
                                                  const float* __restrict__ units,
                                                  unsigned short* __restrict__ psums,
                                                  float* __restrict__ pcnts,
                                                  float* __restrict__ inv_norms,
                                                  unsigned short* __restrict__ xn,
                                                  int write_xn) {
    __shared__ unsigned short xrc[256 * 74];   // [row][ch] bf16, pad 74 halves
    __shared__ unsigned short smn[KK * 72];    // mn (score phase); xT after
    __shared__ unsigned int lidx[64];          // idx bytes, 256 rows
    __shared__ float lcnt[256];
    __shared__ float sInv[256];
    unsigned int* xrc32 = (unsigned int*)xrc;

    const int tid = threadIdx.x, wave = tid >> 6, lane = tid & 63;
    const int quad = lane >> 4, l15 = lane & 15;
    const int rowbase = blockIdx.x * 256;
    const int b = rowbase >> 16, p0 = rowbase & 65535;
    const float* xb = x + (((size_t)(b * 64)) << 16) + p0;

    if (tid < 256) lcnt[tid] = 0.f;

    // ---- mn table in-block: row k = tid>>1, half = tid&1 (32 ch each) ----
    {
        int row = tid >> 1, half = tid & 1;
        const float* up = units + row * 64 + half * 32;
        float4 uv[8];
        float ss = 0.f;
#pragma unroll
        for (int i = 0; i < 8; i++) {
            uv[i] = *(const float4*)(up + i * 4);
            ss += uv[i].x * uv[i].x + uv[i].y * uv[i].y
                + uv[i].z * uv[i].z + uv[i].w * uv[i].w;
        }
        ss += __shfl_xor(ss, 1, 64);
        float invn = 1.0f / fmaxf(sqrtf(ss), 1e-12f);
        unsigned* s32 = (unsigned*)smn;
        int base = row * 36 + half * 16;
#pragma unroll
        for (int i = 0; i < 8; i++) {
            s32[base + i * 2]     = (unsigned)f2bf(uv[i].x * invn) | ((unsigned)f2bf(uv[i].y * invn) << 16);
            s32[base + i * 2 + 1] = (unsigned)f2bf(uv[i].z * invn) | ((unsigned)f2bf(uv[i].w * invn) << 16);
        }
    }

    // ---- stage x -> bf16 LDS (channel-pair packed; stride-37 u32 is 2-way) --
    {
        int cp = tid >> 4, rq = tid & 15;
        const float* xc0 = xb + (((size_t)(cp * 2)) << 16);
        const float* xc1 = xb + (((size_t)(cp * 2 + 1)) << 16);
#pragma unroll
        for (int i = 0; i < 4; i++) {
            int rg = rq + i * 16;
            float4 v0 = *(const float4*)(xc0 + rg * 4);
            float4 v1 = *(const float4*)(xc1 + rg * 4);
            xrc32[(rg * 4 + 0) * 37 + cp] = (unsigned)f2bf(v0.x) | ((unsigned)f2bf(v1.x) << 16);
            xrc32[(rg * 4 + 1) * 37 + cp] = (unsigned)f2bf(v0.y) | ((unsigned)f2bf(v1.y) << 16);
            xrc32[(rg * 4 + 2) * 37 + cp] = (unsigned)f2bf(v0.z) | ((unsigned)f2bf(v1.z) << 16);
            xrc32[(rg * 4 + 3) * 37 + cp] = (unsigned)f2bf(v0.w) | ((unsigned)f2bf(v1.w) << 16);
        }
    }
    __syncthreads();

    // ---- norms: 2 threads per row, pair-reduce via shfl_xor(1) ----
    {
        int row = tid >> 1, half = tid & 1;
        float ss = 0.f;
#pragma unroll
        for (int i = 0; i < 16; i++) {
            unsigned u = xrc32[row * 37 + half * 16 + i];
            float f0 = bf2f(u & 0xffffu), f1 = bf2f(u >> 16);
            ss += f0 * f0 + f1 * f1;
        }
        ss += __shfl_xor(ss, 1, 64);
        if (half == 0) {
            float invv = 1.0f / fmaxf(sqrtf(ss), 1e-12f);
            sInv[row] = invv;
            if (!write_xn) inv_norms[rowbase + row] = invv;
        }
    }
    __syncthreads();

    // ---- score + argmax (bias 16 seeded as MFMA C-input; raw x scale-inv) --
#pragma unroll
    for (int mt = 0; mt < 2; mt++) {
        int rloc = wave * 32 + mt * 16 + l15;
        U8 a0, a1;
#pragma unroll
        for (int i = 0; i < 4; i++) {
            a0.u[i] = xrc32[rloc * 37 + quad * 4 + i];
            a1.u[i] = xrc32[rloc * 37 + 16 + quad * 4 + i];
        }
        int best[4] = {0, 0, 0, 0};
        for (int nt = 0; nt < 16; nt++) {
            const unsigned short* bp = &smn[(nt * 16 + l15) * 72 + quad * 8];
            short8 b0 = *(const short8*)bp;
            short8 b1 = *(const short8*)(bp + 32);
            floatx4 acc = {16.f, 16.f, 16.f, 16.f};
            acc = MFMA16(a0.v, b0, acc);
            acc = MFMA16(a1.v, b1, acc);
#pragma unroll
            for (int rg = 0; rg < 4; rg++) {
                int pk = (__float_as_int(acc[rg]) & ~255) | (nt * 16 + l15);
                best[rg] = max(best[rg], pk);
            }
        }
#pragma unroll
        for (int off = 1; off <= 8; off <<= 1)
#pragma unroll
            for (int rg = 0; rg < 4; rg++)
                best[rg] = max(best[rg], __shfl_xor(best[rg], off, 64));
        if (l15 == 0) {
            unsigned v = (unsigned)(best[0] & 255) | ((unsigned)(best[1] & 255) << 8)
                       | ((unsigned)(best[2] & 255) << 16) | ((unsigned)(best[3] & 255) << 24);
            lidx[wave * 8 + mt * 4 + quad] = v;
        }
    }

    // ---- xn write: fully coalesced uint2 (512B/instr/wave) ----
    if (write_xn) {
        unsigned int* xnu = (unsigned int*)xn + (size_t)rowbase * 32;
#pragma unroll
        for (int i = 0; i < 8; i++) {
            int idx2 = i * 512 + tid;            // uint2 index
            int row = idx2 >> 4, c2 = idx2 & 15;
            unsigned u0 = xrc32[row * 37 + c2 * 2];
            unsigned u1 = xrc32[row * 37 + c2 * 2 + 1];
            float fv = sInv[row];
            uint2 w;
            w.x = (unsigned)f2bf(bf2f(u0 & 0xffffu) * fv) | ((unsigned)f2bf(bf2f(u0 >> 16) * fv) << 16);
            w.y = (unsigned)f2bf(bf2f(u1 & 0xffffu) * fv) | ((unsigned)f2bf(bf2f(u1 >> 16) * fv) << 16);
            *(uint2*)(xnu + (size_t)idx2 * 2) = w;
        }
    }
    __syncthreads();   // all score reads of smn done; safe to overwrite

    // ---- transpose xrc -> xT[64][264] reusing smn's buffer ----
    {
        int ch = tid >> 3, rb = tid & 7;
        unsigned short* xT = smn;
        const int cb = ch * 264, rbb = rb * 32;
#pragma unroll
        for (int w = 0; w < 4; w++) {
            int wq = ((w + rb) & 3) * 8;
            short8 t;
#pragma unroll
            for (int j = 0; j < 8; j++)
                t[j] = (short)xrc[(rbb + wq + j) * 74 + ch];
            *(short8*)&xT[cb + rbb + wq] = t;
        }
    }
    __syncthreads();

    // ---- segment-sum via one-hot MFMA: 8 cluster-groups (1/wave) x 4 ch-
    // quarters; one-hot built 16x/thread, bytes extracted once per ks ----
    {
        const unsigned short* xT = smn;
        floatx4 acc[2][4] = {{{0.f,0.f,0.f,0.f},{0.f,0.f,0.f,0.f},{0.f,0.f,0.f,0.f},{0.f,0.f,0.f,0.f}},
                             {{0.f,0.f,0.f,0.f},{0.f,0.f,0.f,0.f},{0.f,0.f,0.f,0.f},{0.f,0.f,0.f,0.f}}};
        for (int ks = 0; ks < 8; ks++) {
            unsigned id01 = lidx[ks * 8 + quad * 2 + 0];
            unsigned id23 = lidx[ks * 8 + quad * 2 + 1];
            unsigned by[8];
            by[0] = id01 & 255u; by[1] = (id01 >> 8) & 255u;
            by[2] = (id01 >> 16) & 255u; by[3] = id01 >> 24;
            by[4] = id23 & 255u; by[5] = (id23 >> 8) & 255u;
            by[6] = (id23 >> 16) & 255u; by[7] = id23 >> 24;
            short8 bf[4];
#pragma unroll
            for (int n = 0; n < 4; n++) {
                int ch = n * 16 + l15;
                bf[n] = *(const short8*)&xT[ch * 264 + ks * 32 + quad * 8];
            }
#pragma unroll
            for (int mtl = 0; mtl < 2; mtl++) {
                unsigned cl = (unsigned)(wave * 32 + mtl * 16 + l15);
                U8 a;
#pragma unroll
                for (int d = 0; d < 4; d++)
                    a.u[d] = (by[2 * d] == cl ? 0x3F80u : 0u)
                           | (by[2 * d + 1] == cl ? 0x3F800000u : 0u);
#pragma unroll
                for (int n = 0; n < 4; n++)
                    acc[mtl][n] = MFMA16(a.v, bf[n], acc[mtl][n]);
            }
        }
        // psums layout: [pb][k*64+ch] -> contiguous 32 KB per block
        unsigned short* ps = psums + (size_t)blockIdx.x * 16384;
#pragma unroll
        for (int mtl = 0; mtl < 2; mtl++) {
            int cl0 = wave * 32 + mtl * 16 + quad * 4;
#pragma unroll
            for (int n = 0; n < 4; n++) {
                int ch = n * 16 + l15;
#pragma unroll
                for (int rg = 0; rg < 4; rg++)
                    ps[(cl0 + rg) * 64 + ch] = f2bf(acc[mtl][n][rg]);
            }
        }
    }
    // ---- counts (256 LDS atomics); pcnts layout [pb][k] ----
    if (tid < 256) {
        unsigned myb = (lidx[tid >> 2] >> ((tid & 3) * 8)) & 255u;
        atomicAdd(&lcnt[myb], 1.0f);
    }
    __syncthreads();
    if (tid < 256) pcnts[blockIdx.x * 256 + tid] = lcnt[tid];
}

// ---------------------------------------------------------------------------
// triple-EMA update (R6-proven). psums [pb][16384]: block k reads each pb's
// 128 B k-slice as full-line uint4 (8 loads/thread, 1024 threads). EMA reads
// units directly; writes m (legacy), mn, mT. grid 256.
// ---------------------------------------------------------------------------
__global__ __launch_bounds__(1024) void k_update3(const float* __restrict__ units,
                                                  float* __restrict__ m,
                                                  unsigned short* __restrict__ mn,
                                                  const unsigned short* __restrict__ psums,
                                                  const float* __restrict__ pcnts,
                                                  unsigned short* __restrict__ mTg) {
    __shared__ float acc8[128 * 68];   // g-stride 68 floats (bank-spread)
    __shared__ float scnt[1024];
    const int k = blockIdx.x, tid = threadIdx.x;
    const uint4* ps4 = (const uint4*)psums;   // pb row = 2048 uint4
    const int col = tid & 7, g = tid >> 3;    // col: uint4 within k-slice

    float s[8] = {0.f,0.f,0.f,0.f,0.f,0.f,0.f,0.f};
#pragma unroll
    for (int i = 0; i < 8; i++) {
        int pb = g + i * 128;
        uint4 v = ps4[(size_t)pb * 2048 + k * 8 + col];
        s[0] += bf2f(v.x & 0xffffu); s[1] += bf2f(v.x >> 16);
        s[2] += bf2f(v.y & 0xffffu); s[3] += bf2f(v.y >> 16);
        s[4] += bf2f(v.z & 0xffffu); s[5] += bf2f(v.z >> 16);
        s[6] += bf2f(v.w & 0xffffu); s[7] += bf2f(v.w >> 16);
    }
#pragma unroll
    for (int j = 0; j < 8; j++) acc8[g * 68 + col * 8 + j] = s[j];
    scnt[tid] = pcnts[tid * 256 + k];
    __syncthreads();

    if (tid < 64) {
        float tot = 0.f;
        for (int g2 = 0; g2 < 128; g2++) tot += acc8[g2 * 68 + tid];
        float cnt = 0.f;
#pragma unroll
        for (int q = 0; q < 16; q++) cnt += scnt[tid + 64 * q];
#pragma unroll
        for (int off = 32; off; off >>= 1) cnt += __shfl_xor(cnt, off, 64);
        float mean = tot / (cnt + 1e-6f);
        float v = units[(k << 6) | tid] * R3_F + mean * E3_F;
        m[(k << 6) | tid] = v;
        mTg[tid * 256 + k] = f2bf(v);
        float ss = v * v;
#pragma unroll
        for (int off = 32; off; off >>= 1) ss += __shfl_xor(ss, off, 64);
        mn[(k << 6) | tid] = f2bf(v / fmaxf(sqrtf(ss), 1e-12f));
    }
}

// ---------------------------------------------------------------------------
// final (fast) v4 (R6-proven): swapped-operand score (S^T) makes P lane-local;
// P redistributed to the PV A-fragment with 4 shfl_xor. Both tables staged
// via coalesced chunk-swizzled b128 copies. LDS 64 KB -> 2 blocks/CU.
// grid 2048 x 512, __launch_bounds__(512,4).
// ---------------------------------------------------------------------------
__global__ __launch_bounds__(512, 4) void k_final_fast(const unsigned short* __restrict__ xn,
                                                       const unsigned short* __restrict__ mn,
                                                       const unsigned short* __restrict__ mTg,
                                                       float* __restrict__ out) {
    __shared__ unsigned short smn[KK * 64];   // [cluster][ch], chunk^=(cluster&7)
    __shared__ unsigned short smT[64 * KK];   // [ch][cluster], chunk^=(ch&7)

    const int tid = threadIdx.x;
    for (int i = tid; i < 2048; i += 512) {
        int row = i >> 3, c = i & 7;
        *(short8*)&smn[row * 64 + ((c ^ (row & 7)) << 3)] = *(const short8*)(mn + i * 8);
    }
    for (int j = tid; j < 2048; j += 512) {
        int ch = j >> 5, cp = j & 31;
        *(short8*)&smT[ch * 256 + ((cp ^ (ch & 7)) << 3)] = *(const short8*)(mTg + j * 8);
    }
    __syncthreads();

    const int wave = tid >> 6, lane = tid & 63;
    const int quad = lane >> 4, l15 = lane & 15;
    const int s7 = l15 & 7;
    const bool hi2 = (quad & 2) != 0, odd = (quad & 1) != 0;

    const int r0 = (blockIdx.x * 8 + wave) * 16;
    const int r = r0 + l15;
    const int b = r0 >> 16, p0 = r0 & 65535;

    short8 a0 = *(const short8*)(xn + (size_t)r * 64 + quad * 8);
    short8 a1 = *(const short8*)(xn + (size_t)r * 64 + 32 + quad * 8);

    float ls = 0.f;
    floatx4 oacc[4] = {{0.f,0.f,0.f,0.f},{0.f,0.f,0.f,0.f},{0.f,0.f,0.f,0.f},{0.f,0.f,0.f,0.f}};

    for (int kt2 = 0; kt2 < 8; kt2++) {
        unsigned W[2][2];
#pragma unroll
        for (int h = 0; h < 2; h++) {
            int kt = kt2 * 2 + h;
            const unsigned short* bp = &smn[(kt * 16 + l15) * 64];
            short8 b0 = *(const short8*)(bp + ((quad ^ s7) << 3));
            short8 b1 = *(const short8*)(bp + (((4 + quad) ^ s7) << 3));
            floatx4 acc = {0.f, 0.f, 0.f, 0.f};
            acc = MFMA16(b0, a0, acc);      // S^T: lane -> row l15, cluster quad*4+rg
            acc = MFMA16(b1, a1, acc);
            float e0 = __expf(acc[0]), e1 = __expf(acc[1]);
            float e2 = __expf(acc[2]), e3 = __expf(acc[3]);
            ls += (e0 + e1) + (e2 + e3);
            W[h][0] = (unsigned)f2bf(e0) | ((unsigned)f2bf(e1) << 16);
            W[h][1] = (unsigned)f2bf(e2) | ((unsigned)f2bf(e3) << 16);
        }
        // redistribute P (held: h*16+quad*4+rg) -> A-frag (needs quad*8+j)
        unsigned memA[2], memB[2];
#pragma unroll
        for (int p = 0; p < 2; p++) {
            unsigned send = hi2 ? W[0][p] : W[1][p];
            unsigned recv = (unsigned)__shfl_xor((int)send, 32, 64);
            unsigned keep = hi2 ? W[1][p] : W[0][p];
            memA[p] = hi2 ? recv : keep;
            memB[p] = hi2 ? keep : recv;
        }
        U8 ap;
#pragma unroll
        for (int p = 0; p < 2; p++) {
            unsigned send2 = odd ? memA[p] : memB[p];
            unsigned recv2 = (unsigned)__shfl_xor((int)send2, 16, 64);
            ap.u[p]     = odd ? recv2 : memA[p];
            ap.u[2 + p] = odd ? memB[p] : recv2;
        }
#pragma unroll
        for (int nt = 0; nt < 4; nt++) {
            short8 bm = *(const short8*)&smT[(nt * 16 + l15) * 256 + (((kt2 * 4 + quad) ^ s7) << 3)];
            oacc[nt] = MFMA16(ap.v, bm, oacc[nt]);
        }
    }

    ls += __shfl_xor(ls, 16, 64);
    ls += __shfl_xor(ls, 32, 64);
    float il = 1.0f / ls;
    float il4[4];
#pragma unroll
    for (int rg = 0; rg < 4; rg++) il4[rg] = __shfl(il, quad * 4 + rg, 64);

#pragma unroll
    for (int nt = 0; nt < 4; nt++) {
        floatx4 w;
#pragma unroll
        for (int rg = 0; rg < 4; rg++) w[rg] = oacc[nt][rg] * il4[rg];
        float* op = out + (((size_t)(b * 64 + nt * 16 + l15)) << 16) + p0 + quad * 4;
        *(floatx4*)op = w;
    }
}

// ---------------------------------------------------------------------------
// final (legacy, small-ws): re-reads x (channel-strided) + inv_norms.
// ---------------------------------------------------------------------------
__global__ __launch_bounds__(512, 4) void k_final_legacy(const float* __restrict__ x,
                                                         const unsigned short* __restrict__ mn,
                                                         const float* __restrict__ m,
                                                         const float* __restrict__ inv_norms,
                                                         float* __restrict__ out) {
    __shared__ unsigned short smn[KK * 72];
    __shared__ unsigned short smT[64 * 264];
    __shared__ unsigned short sP[8 * 640];

    const int tid = threadIdx.x;
    for (int i = tid; i < KK * 64; i += 512) smn[(i >> 6) * 72 + (i & 63)] = mn[i];
    for (int i = tid; i < KK * 64; i += 512) smT[(i & 63) * 264 + (i >> 6)] = f2bf(m[i]);
    __syncthreads();

    const int wave = tid >> 6, lane = tid & 63;
    const int quad = lane >> 4, l15 = lane & 15;

    const int r0 = (blockIdx.x * 8 + wave) * 16;
    const int r = r0 + l15;
    const int b = r0 >> 16, p0 = r0 & 65535;
    const float* xp = x + (((size_t)(b * 64)) << 16) + (p0 + l15);

    float xv[16];
#pragma unroll
    for (int j = 0; j < 8; j++) {
        xv[j]     = xp[((size_t)(quad * 8 + j)) << 16];
        xv[8 + j] = xp[((size_t)(32 + quad * 8 + j)) << 16];
    }
    const float inv = inv_norms[r];
    short8 a0, a1;
#pragma unroll
    for (int j = 0; j < 8; j++) {
        a0[j] = (short)f2bf(xv[j] * inv);
        a1[j] = (short)f2bf(xv[8 + j] * inv);
    }

    unsigned short* Pw = sP + wave * 640;
    float ls[4] = {0.f, 0.f, 0.f, 0.f};
    floatx4 oacc[4] = {{0.f,0.f,0.f,0.f},{0.f,0.f,0.f,0.f},{0.f,0.f,0.f,0.f},{0.f,0.f,0.f,0.f}};

    for (int kt2 = 0; kt2 < 8; kt2++) {
#pragma unroll
        for (int h = 0; h < 2; h++) {
            int kt = kt2 * 2 + h;
            const unsigned short* bp = &smn[(kt * 16 + l15) * 72 + quad * 8];
            short8 b0 = *(const short8*)bp;
            short8 b1 = *(const short8*)(bp + 32);
            floatx4 acc = {0.f, 0.f, 0.f, 0.f};
            acc = MFMA16(a0, b0, acc);
            acc = MFMA16(a1, b1, acc);
#pragma unroll
            for (int rg = 0; rg < 4; rg++) {
                float e = __expf(acc[rg]);
                ls[rg] += e;
                Pw[(quad * 4 + rg) * 40 + h * 16 + l15] = f2bf(e);
            }
        }
        __threadfence_block();
        short8 ap = *(const short8*)&Pw[l15 * 40 + quad * 8];
#pragma unroll
        for (int nt = 0; nt < 4; nt++) {
            short8 bm = *(const short8*)&smT[(nt * 16 + l15) * 264 + kt2 * 32 + quad * 8];
            oacc[nt] = MFMA16(ap, bm, oacc[nt]);
        }
    }

#pragma unroll
    for (int off = 1; off <= 8; off <<= 1)
#pragma unroll
        for (int rg = 0; rg < 4; rg++) ls[rg] += __shfl_xor(ls[rg], off, 64);

    float il[4];
#pragma unroll
    for (int rg = 0; rg < 4; rg++) il[rg] = 1.0f / ls[rg];

#pragma unroll
    for (int nt = 0; nt < 4; nt++) {
        floatx4 w;
#pragma unroll
        for (int rg = 0; rg < 4; rg++) w[rg] = oacc[nt][rg] * il[rg];
        float* op = out + (((size_t)(b * 64 + nt * 16 + l15)) << 16) + p0 + quad * 4;
        *(floatx4*)op = w;
    }
}

// ---------------------------------------------------------------------------
extern "C" void kernel_launch(void* const* d_in, const int* in_sizes, int n_in,
                              void* d_out, int out_size, void* d_ws, size_t ws_size,
                              hipStream_t stream) {
    (void)in_sizes; (void)n_in; (void)out_size;
    const float* x     = (const float*)d_in[0];
    const float* units = (const float*)d_in[1];
    float* out = (float*)d_out;

    // ws: m f32[16384] | inv f32[NROW] | pcnts f32[1024*256] |
    //     psums bf16[1024*16384] | mn bf16[16384] | mT bf16[16384] | xn bf16[NROW*64]
    float* W = (float*)d_ws;
    float* m     = W;
    float* inv   = W + 16384;
    float* pcnts = W + 16384 + NROW;
    unsigned short* psums = (unsigned short*)(pcnts + NPART * 256);
    unsigned short* mn = psums + (size_t)NPART * 16384;
    unsigned short* mT = mn + 16384;
    unsigned short* xn = mT + 16384;

    size_t need_fast = (size_t)(16384 + NROW + NPART * 256) * 4
                     + ((size_t)NPART * 16384 + 32768) * 2
                     + (size_t)NROW * 64 * 2;
    int fast = (ws_size >= need_fast) ? 1 : 0;

    k_pass1<<<NPART, 512, 0, stream>>>(x, units, psums, pcnts, inv, xn, fast);
    k_update3<<<KK, 1024, 0, stream>>>(units, m, mn, psums, pcnts, mT);
    if (fast) k_final_fast<<<2048, 512, 0, stream>>>(xn, mn, mT, out);
    else      k_final_legacy<<<2048, 512, 0, stream>>>(x, mn, m, inv, out);
}